// Round 1
// baseline (1949.409 us; speedup 1.0000x reference)
//
#include <hip/hip_runtime.h>
#include <hip/hip_bf16.h>
#include <math.h>

#define TT 64
#define NN 2000
#define FIN 32
#define HH 64
#define CC 10
#define EE 32000
#define ETOT 34000   // E + N self loops
#define THL 4096     // T*H
#define EPSBN 1e-5f

// ---------------- workspace layout (float offsets) ----------------
#define OFF_WC   0u          // 4,000,000
#define OFF_XA   4000000u    // 8,192,000  [N,T,H]
#define OFF_XB   12192000u   // 8,192,000
#define OFF_XC   20384000u   // 8,192,000
#define OFF_DEG  28576000u   // 2048
#define OFF_H1   28578048u   // 128,000
#define OFF_CNT  28706048u   // int 2048
#define OFF_CUR  28708096u   // int 2048
#define OFF_OFF  28710144u   // int 2064
#define OFF_CSRS 28712208u   // int 34016
#define OFF_CSRN 28746224u   // float 34016
// total ≈ 28,780,240 floats ≈ 110 MB

__device__ __forceinline__ float fsigmoid(float x) { return 1.f / (1.f + __expf(-x)); }

// ---------------- CSR build ----------------
__global__ void k_zero(int* cnt, int* cur, float* deg) {
    int i = blockIdx.x * 256 + threadIdx.x;
    if (i < 2048) { cnt[i] = 0; cur[i] = 0; deg[i] = 0.f; }
}

__global__ void k_count(const int* __restrict__ ei, const float* __restrict__ ew,
                        int* cnt, float* deg) {
    int e = blockIdx.x * 256 + threadIdx.x;
    if (e < ETOT) {
        int dst; float w;
        if (e < EE) { dst = ei[EE + e]; w = ew[e]; }
        else        { dst = e - EE;     w = 1.f; }
        atomicAdd(&cnt[dst], 1);
        atomicAdd(&deg[dst], w);
    }
}

__global__ __launch_bounds__(1024) void k_scan(const int* __restrict__ cnt, int* off) {
    __shared__ int s[2048];
    int tid = threadIdx.x;
    s[tid]        = (tid        < NN) ? cnt[tid]        : 0;
    s[tid + 1024] = (tid + 1024 < NN) ? cnt[tid + 1024] : 0;
    __syncthreads();
    for (int d = 1; d < 2048; d <<= 1) {
        int idx = (tid + 1) * (d << 1) - 1;
        if (idx < 2048) s[idx] += s[idx - d];
        __syncthreads();
    }
    if (tid == 0) s[2047] = 0;
    __syncthreads();
    for (int d = 1024; d >= 1; d >>= 1) {
        int idx = (tid + 1) * (d << 1) - 1;
        if (idx < 2048) { int t = s[idx - d]; s[idx - d] = s[idx]; s[idx] += t; }
        __syncthreads();
    }
    off[tid] = s[tid];
    off[tid + 1024] = s[tid + 1024];
}

__global__ void k_fill(const int* __restrict__ ei, const float* __restrict__ ew,
                       const float* __restrict__ deg, const int* __restrict__ off,
                       int* cur, int* csr_src, float* csr_nrm) {
    int e = blockIdx.x * 256 + threadIdx.x;
    if (e < ETOT) {
        int src, dst; float w;
        if (e < EE) { src = ei[e]; dst = ei[EE + e]; w = ew[e]; }
        else        { src = dst = e - EE;            w = 1.f; }
        float ds = rsqrtf(fmaxf(deg[src], 1e-12f));
        float dd = rsqrtf(fmaxf(deg[dst], 1e-12f));
        int pos = off[dst] + atomicAdd(&cur[dst], 1);
        csr_src[pos] = src;
        csr_nrm[pos] = ds * w * dd;
    }
}

// ---------------- softmax over causal_weight rows ----------------
__global__ __launch_bounds__(256) void k_softmax(const float* __restrict__ CW,
                                                 float* __restrict__ WC) {
    __shared__ float row[NN];
    __shared__ float red[256];
    int r = blockIdx.x, tid = threadIdx.x;
    const float* in = CW + (size_t)r * NN;
    float mx = -1e30f;
    for (int i = tid; i < NN; i += 256) { float v = in[i]; row[i] = v; mx = fmaxf(mx, v); }
    red[tid] = mx; __syncthreads();
    for (int s = 128; s > 0; s >>= 1) {
        if (tid < s) red[tid] = fmaxf(red[tid], red[tid + s]);
        __syncthreads();
    }
    mx = red[0]; __syncthreads();
    float sm = 0.f;
    for (int i = tid; i < NN; i += 256) { float e = __expf(row[i] - mx); row[i] = e; sm += e; }
    red[tid] = sm; __syncthreads();
    for (int s = 128; s > 0; s >>= 1) {
        if (tid < s) red[tid] += red[tid + s];
        __syncthreads();
    }
    float inv = 1.f / red[0];
    float* out = WC + (size_t)r * NN;
    for (int i = tid; i < NN; i += 256) out[i] = row[i] * inv;
}

// ---------------- lin_in: relu(x_seq @ W^T + b) -> [N,T,H] ----------------
__global__ __launch_bounds__(256) void k_lin_in(const float* __restrict__ XS,
                                                const float* __restrict__ W,
                                                const float* __restrict__ b,
                                                float* __restrict__ OUT) {
    __shared__ float Wt[FIN][HH + 1];
    int tid = threadIdx.x;
    for (int i = tid; i < HH * FIN; i += 256) {
        int o = i >> 5, f = i & 31;
        Wt[f][o] = W[i];
    }
    __syncthreads();
    int n = blockIdx.x;
    int wv = tid >> 6, lane = tid & 63;
    for (int t = wv; t < TT; t += 4) {
        const float4* xr = (const float4*)(XS + ((size_t)t * NN + n) * FIN);
        float acc = b[lane];
#pragma unroll
        for (int q = 0; q < 8; ++q) {
            float4 v = xr[q];
            acc += v.x * Wt[q * 4 + 0][lane] + v.y * Wt[q * 4 + 1][lane]
                 + v.z * Wt[q * 4 + 2][lane] + v.w * Wt[q * 4 + 3][lane];
        }
        OUT[((size_t)n * TT + t) * HH + lane] = fmaxf(acc, 0.f);
    }
}

// ---------------- dense GEMM: XAGG[2000,4096] = WC[2000,2000] @ X[2000,4096] ----------------
__global__ __launch_bounds__(256) void k_gemm(const float* __restrict__ A,
                                              const float* __restrict__ B,
                                              float* __restrict__ Cm) {
    __shared__ alignas(16) float As[16][64];
    __shared__ alignas(16) float Bs[16][64];
    int tid = threadIdx.x;
    int bn = blockIdx.x, bm = blockIdx.y;
    int tx = tid & 15, ty = tid >> 4;
    float acc[4][4] = {};
    int arow = tid >> 2, acq = tid & 3;
    int brow = tid >> 4, bcq = tid & 15;
    int agr = bm * 64 + arow;
    for (int kt = 0; kt < 125; ++kt) {
        float4 av = make_float4(0.f, 0.f, 0.f, 0.f);
        if (agr < NN)
            av = *(const float4*)(A + (size_t)agr * NN + kt * 16 + acq * 4);
        As[acq * 4 + 0][arow] = av.x;
        As[acq * 4 + 1][arow] = av.y;
        As[acq * 4 + 2][arow] = av.z;
        As[acq * 4 + 3][arow] = av.w;
        float4 bv = *(const float4*)(B + (size_t)(kt * 16 + brow) * THL + bn * 64 + bcq * 4);
        *(float4*)&Bs[brow][bcq * 4] = bv;
        __syncthreads();
#pragma unroll
        for (int k = 0; k < 16; ++k) {
            const float4 a = *(const float4*)&As[k][ty * 4];
            const float4 b = *(const float4*)&Bs[k][tx * 4];
            acc[0][0] += a.x * b.x; acc[0][1] += a.x * b.y; acc[0][2] += a.x * b.z; acc[0][3] += a.x * b.w;
            acc[1][0] += a.y * b.x; acc[1][1] += a.y * b.y; acc[1][2] += a.y * b.z; acc[1][3] += a.y * b.w;
            acc[2][0] += a.z * b.x; acc[2][1] += a.z * b.y; acc[2][2] += a.z * b.z; acc[2][3] += a.z * b.w;
            acc[3][0] += a.w * b.x; acc[3][1] += a.w * b.y; acc[3][2] += a.w * b.z; acc[3][3] += a.w * b.w;
        }
        __syncthreads();
    }
#pragma unroll
    for (int i = 0; i < 4; ++i) {
        int gr = bm * 64 + ty * 4 + i;
        if (gr < NN) {
            float4 o = make_float4(acc[i][0], acc[i][1], acc[i][2], acc[i][3]);
            *(float4*)(Cm + (size_t)gr * THL + bn * 64 + tx * 4) = o;
        }
    }
}

// ---------------- fusion: relu([x | x_agg] @ W^T + b) ----------------
__global__ __launch_bounds__(256) void k_fusion(const float* __restrict__ X,
                                                const float* __restrict__ XA,
                                                const float* __restrict__ W,
                                                const float* __restrict__ b,
                                                float* __restrict__ OUT) {
    __shared__ float Wt[2 * HH][HH + 1];
    int tid = threadIdx.x;
    for (int i = tid; i < HH * 2 * HH; i += 256) {
        int o = i >> 7, f = i & 127;
        Wt[f][o] = W[i];
    }
    __syncthreads();
    int n = blockIdx.x;
    int wv = tid >> 6, lane = tid & 63;
    for (int t = wv; t < TT; t += 4) {
        const float4* xr = (const float4*)(X + ((size_t)n * TT + t) * HH);
        const float4* ar = (const float4*)(XA + ((size_t)n * TT + t) * HH);
        float acc = b[lane];
#pragma unroll
        for (int q = 0; q < 16; ++q) {
            float4 v = xr[q];
            acc += v.x * Wt[q * 4 + 0][lane] + v.y * Wt[q * 4 + 1][lane]
                 + v.z * Wt[q * 4 + 2][lane] + v.w * Wt[q * 4 + 3][lane];
        }
#pragma unroll
        for (int q = 0; q < 16; ++q) {
            float4 v = ar[q];
            acc += v.x * Wt[64 + q * 4 + 0][lane] + v.y * Wt[64 + q * 4 + 1][lane]
                 + v.z * Wt[64 + q * 4 + 2][lane] + v.w * Wt[64 + q * 4 + 3][lane];
        }
        OUT[((size_t)n * TT + t) * HH + lane] = fmaxf(acc, 0.f);
    }
}

// ---------------- GCN xw: row @ W^T (no bias) ----------------
__global__ __launch_bounds__(256) void k_xw(const float* __restrict__ IN,
                                            const float* __restrict__ W,
                                            float* __restrict__ OUT) {
    __shared__ float Wt[HH][HH + 1];
    int tid = threadIdx.x;
    for (int i = tid; i < HH * HH; i += 256) {
        int o = i >> 6, f = i & 63;
        Wt[f][o] = W[i];
    }
    __syncthreads();
    int n = blockIdx.x;
    int wv = tid >> 6, lane = tid & 63;
    for (int t = wv; t < TT; t += 4) {
        const float4* xr = (const float4*)(IN + ((size_t)n * TT + t) * HH);
        float acc = 0.f;
#pragma unroll
        for (int q = 0; q < 16; ++q) {
            float4 v = xr[q];
            acc += v.x * Wt[q * 4 + 0][lane] + v.y * Wt[q * 4 + 1][lane]
                 + v.z * Wt[q * 4 + 2][lane] + v.w * Wt[q * 4 + 3][lane];
        }
        OUT[((size_t)n * TT + t) * HH + lane] = acc;
    }
}

// ---------------- GCN aggregate (CSR) + bias + BN + relu ----------------
__global__ __launch_bounds__(256) void k_agg(const float* __restrict__ XW,
                                             const int* __restrict__ off,
                                             const int* __restrict__ csr_src,
                                             const float* __restrict__ csr_nrm,
                                             const float* __restrict__ bias,
                                             const float* __restrict__ g,
                                             const float* __restrict__ bb,
                                             const float* __restrict__ m,
                                             const float* __restrict__ v,
                                             float* __restrict__ OUT) {
    int dst = blockIdx.x, tid = threadIdx.x;
    float acc[16];
#pragma unroll
    for (int k = 0; k < 16; ++k) acc[k] = 0.f;
    int beg = off[dst], end = off[dst + 1];
    for (int e = beg; e < end; ++e) {
        int src = csr_src[e];
        float w = csr_nrm[e];
        const float* xr = XW + (size_t)src * THL;
#pragma unroll
        for (int k = 0; k < 16; ++k) acc[k] += w * xr[tid + k * 256];
    }
    int h = tid & 63;
    float bs = bias[h];
    float scale = rsqrtf(v[h] + EPSBN) * g[h];
    float mean = m[h], beta = bb[h];
    float* orow = OUT + (size_t)dst * THL;
#pragma unroll
    for (int k = 0; k < 16; ++k) {
        float val = (acc[k] + bs - mean) * scale + beta;
        orow[tid + k * 256] = fmaxf(val, 0.f);
    }
}

// ---------------- fused 2-layer GRU (node-parallel, all T in one kernel) ----------------
#define GNB 8
__device__ __forceinline__ void gru_gates(const float (*in)[HH], const float (*h)[HH],
                                          const float* __restrict__ wih, const float* __restrict__ whh,
                                          const float* __restrict__ bih, const float* __restrict__ bhh,
                                          float (*gi)[192], float (*gh)[192], int tid) {
    if (tid < 192) {
        int j = tid;
        const float4* wi = (const float4*)(wih + j * HH);
        const float4* wh = (const float4*)(whh + j * HH);
        float accI[GNB], accH[GNB];
        float bi = bih[j], bh = bhh[j];
#pragma unroll
        for (int n = 0; n < GNB; ++n) { accI[n] = bi; accH[n] = bh; }
#pragma unroll
        for (int q = 0; q < 16; ++q) {
            float4 a = wi[q], b = wh[q];
#pragma unroll
            for (int n = 0; n < GNB; ++n) {
                float4 x4 = ((const float4*)in[n])[q];
                float4 h4 = ((const float4*)h[n])[q];
                accI[n] += a.x * x4.x + a.y * x4.y + a.z * x4.z + a.w * x4.w;
                accH[n] += b.x * h4.x + b.y * h4.y + b.z * h4.z + b.w * h4.w;
            }
        }
#pragma unroll
        for (int n = 0; n < GNB; ++n) { gi[n][j] = accI[n]; gh[n][j] = accH[n]; }
    }
}

__device__ __forceinline__ void gru_update(float (*h)[HH], const float (*gi)[192],
                                           const float (*gh)[192], int tid) {
    for (int i = tid; i < GNB * HH; i += 256) {
        int n = i >> 6, j = i & 63;
        float r = fsigmoid(gi[n][j] + gh[n][j]);
        float z = fsigmoid(gi[n][64 + j] + gh[n][64 + j]);
        float nn = tanhf(gi[n][128 + j] + r * gh[n][128 + j]);
        h[n][j] = (1.f - z) * nn + z * h[n][j];
    }
}

__global__ __launch_bounds__(256) void k_gru(const float* __restrict__ X,
                                             const float* __restrict__ wih0, const float* __restrict__ whh0,
                                             const float* __restrict__ bih0, const float* __restrict__ bhh0,
                                             const float* __restrict__ wih1, const float* __restrict__ whh1,
                                             const float* __restrict__ bih1, const float* __restrict__ bhh1,
                                             float* __restrict__ hout) {
    __shared__ alignas(16) float xs[GNB][HH];
    __shared__ alignas(16) float h0[GNB][HH];
    __shared__ alignas(16) float h1[GNB][HH];
    __shared__ float gi[GNB][192];
    __shared__ float gh[GNB][192];
    int tid = threadIdx.x;
    int nb0 = blockIdx.x * GNB;
    for (int i = tid; i < GNB * HH; i += 256) {
        ((float*)h0)[i] = 0.f;
        ((float*)h1)[i] = 0.f;
    }
    __syncthreads();
    for (int t = 0; t < TT; ++t) {
        for (int i = tid; i < GNB * HH; i += 256) {
            int n = i >> 6, j = i & 63;
            xs[n][j] = X[((size_t)(nb0 + n) * TT + t) * HH + j];
        }
        __syncthreads();
        gru_gates(xs, h0, wih0, whh0, bih0, bhh0, gi, gh, tid);
        __syncthreads();
        gru_update(h0, gi, gh, tid);
        __syncthreads();
        gru_gates(h0, h1, wih1, whh1, bih1, bhh1, gi, gh, tid);
        __syncthreads();
        gru_update(h1, gi, gh, tid);
        __syncthreads();
    }
    for (int i = tid; i < GNB * HH; i += 256) {
        int n = i >> 6, j = i & 63;
        hout[(size_t)(nb0 + n) * HH + j] = h1[n][j];
    }
}

// ---------------- head: BN + relu + linear + log_softmax ----------------
__global__ __launch_bounds__(256) void k_head(const float* __restrict__ Hf,
                                              const float* __restrict__ g, const float* __restrict__ b,
                                              const float* __restrict__ m, const float* __restrict__ v,
                                              const float* __restrict__ W, const float* __restrict__ wb,
                                              float* __restrict__ out) {
    __shared__ float hb[4][HH];
    __shared__ float lg[4][CC];
    int tid = threadIdx.x;
    int n0 = blockIdx.x * 4;
    int wv = tid >> 6, lane = tid & 63;
    int n = n0 + wv;
    float x = Hf[(size_t)n * HH + lane];
    x = (x - m[lane]) * rsqrtf(v[lane] + EPSBN) * g[lane] + b[lane];
    hb[wv][lane] = fmaxf(x, 0.f);
    __syncthreads();
    if (tid < 4 * CC) {
        int nn = tid / CC, c = tid % CC;
        float acc = wb[c];
        for (int f = 0; f < HH; ++f) acc += hb[nn][f] * W[c * HH + f];
        lg[nn][c] = acc;
    }
    __syncthreads();
    if (tid < 4 * CC) {
        int nn = tid / CC, c = tid % CC;
        float mx = -1e30f;
#pragma unroll
        for (int i = 0; i < CC; ++i) mx = fmaxf(mx, lg[nn][i]);
        float s = 0.f;
#pragma unroll
        for (int i = 0; i < CC; ++i) s += __expf(lg[nn][i] - mx);
        out[(size_t)(n0 + nn) * CC + c] = lg[nn][c] - mx - __logf(s);
    }
}

// ---------------- launch ----------------
extern "C" void kernel_launch(void* const* d_in, const int* in_sizes, int n_in,
                              void* d_out, int out_size, void* d_ws, size_t ws_size,
                              hipStream_t stream) {
    const float* x_seq     = (const float*)d_in[0];
    const int*   edge_idx  = (const int*)d_in[1];
    const float* edge_w    = (const float*)d_in[2];
    const float* causal_w  = (const float*)d_in[3];
    const float* lin_in_w  = (const float*)d_in[4];
    const float* lin_in_b  = (const float*)d_in[5];
    const float* fusion_w  = (const float*)d_in[6];
    const float* fusion_b  = (const float*)d_in[7];
    const float* gcn_w0    = (const float*)d_in[8];
    const float* gcn_b0    = (const float*)d_in[9];
    const float* gcn_w1    = (const float*)d_in[10];
    const float* gcn_b1    = (const float*)d_in[11];
    const float* bn0_g = (const float*)d_in[12], *bn0_b = (const float*)d_in[13];
    const float* bn0_m = (const float*)d_in[14], *bn0_v = (const float*)d_in[15];
    const float* bn1_g = (const float*)d_in[16], *bn1_b = (const float*)d_in[17];
    const float* bn1_m = (const float*)d_in[18], *bn1_v = (const float*)d_in[19];
    const float* wih0 = (const float*)d_in[20], *whh0 = (const float*)d_in[21];
    const float* bih0 = (const float*)d_in[22], *bhh0 = (const float*)d_in[23];
    const float* wih1 = (const float*)d_in[24], *whh1 = (const float*)d_in[25];
    const float* bih1 = (const float*)d_in[26], *bhh1 = (const float*)d_in[27];
    const float* bno_g = (const float*)d_in[28], *bno_b = (const float*)d_in[29];
    const float* bno_m = (const float*)d_in[30], *bno_v = (const float*)d_in[31];
    const float* lout_w = (const float*)d_in[32], *lout_b = (const float*)d_in[33];
    float* out = (float*)d_out;

    float* wsf = (float*)d_ws;
    float* WC  = wsf + OFF_WC;
    float* XA  = wsf + OFF_XA;
    float* XB  = wsf + OFF_XB;
    float* XC  = wsf + OFF_XC;
    float* DEG = wsf + OFF_DEG;
    float* H1F = wsf + OFF_H1;
    int* CNT   = (int*)(wsf + OFF_CNT);
    int* CUR   = (int*)(wsf + OFF_CUR);
    int* OFFP  = (int*)(wsf + OFF_OFF);
    int* CSRS  = (int*)(wsf + OFF_CSRS);
    float* CSRN = wsf + OFF_CSRN;

    // CSR + degree build
    k_zero<<<8, 256, 0, stream>>>(CNT, CUR, DEG);
    k_count<<<(ETOT + 255) / 256, 256, 0, stream>>>(edge_idx, edge_w, CNT, DEG);
    k_scan<<<1, 1024, 0, stream>>>(CNT, OFFP);
    k_fill<<<(ETOT + 255) / 256, 256, 0, stream>>>(edge_idx, edge_w, DEG, OFFP, CUR, CSRS, CSRN);

    // causal softmax
    k_softmax<<<NN, 256, 0, stream>>>(causal_w, WC);
    // lin_in -> XA [N,T,H]
    k_lin_in<<<NN, 256, 0, stream>>>(x_seq, lin_in_w, lin_in_b, XA);
    // x_agg = WC @ XA -> XB
    dim3 gg(THL / 64, (NN + 63) / 64);
    k_gemm<<<gg, 256, 0, stream>>>(WC, XA, XB);
    // fusion -> XC
    k_fusion<<<NN, 256, 0, stream>>>(XA, XB, fusion_w, fusion_b, XC);
    // GCN layer 0: XC -> XB (xw) -> XA (agg+bn+relu)
    k_xw<<<NN, 256, 0, stream>>>(XC, gcn_w0, XB);
    k_agg<<<NN, 256, 0, stream>>>(XB, OFFP, CSRS, CSRN, gcn_b0, bn0_g, bn0_b, bn0_m, bn0_v, XA);
    // GCN layer 1: XA -> XB -> XC
    k_xw<<<NN, 256, 0, stream>>>(XA, gcn_w1, XB);
    k_agg<<<NN, 256, 0, stream>>>(XB, OFFP, CSRS, CSRN, gcn_b1, bn1_g, bn1_b, bn1_m, bn1_v, XC);
    // fused 2-layer GRU over all T
    k_gru<<<NN / GNB, 256, 0, stream>>>(XC, wih0, whh0, bih0, bhh0, wih1, whh1, bih1, bhh1, H1F);
    // head
    k_head<<<NN / 4, 256, 0, stream>>>(H1F, bno_g, bno_b, bno_m, bno_v, lout_w, lout_b, out);
}

// Round 2
// 1530.328 us; speedup vs baseline: 1.2739x; 1.2739x over previous
//
#include <hip/hip_runtime.h>
#include <hip/hip_bf16.h>
#include <math.h>

#define TT 64
#define NN 2000
#define FIN 32
#define HH 64
#define CC 10
#define EE 32000
#define ETOT 34000   // E + N self loops
#define THL 4096     // T*H
#define EPSBN 1e-5f
#define CHT 16       // GRU time-chunk

// ---------------- workspace layout (float offsets) ----------------
#define OFF_WC   0u          // 4,000,000
#define OFF_XA   4000000u    // 8,192,000  [N,T,H]
#define OFF_XB   12192000u   // 8,192,000  (also GI chunk buffer: 2000*16*192 = 6,144,000)
#define OFF_XC   20384000u   // 8,192,000
#define OFF_DEG  28576000u   // 2048
#define OFF_H1   28578048u   // 128,000 (unused, kept for layout stability)
#define OFF_CNT  28706048u   // int 2048
#define OFF_CUR  28708096u   // int 2048
#define OFF_OFF  28710144u   // int 2064
#define OFF_CSRS 28712208u   // int 34016
#define OFF_CSRN 28746224u   // float 34016
#define OFF_HST  28780240u   // float 128,000  (GRU h-state between chunks / final h)
// total ≈ 28,908,240 floats ≈ 115.6 MB

__device__ __forceinline__ float fsigmoid(float x) { return 1.f / (1.f + __expf(-x)); }

// ---------------- CSR build ----------------
__global__ void k_zero(int* cnt, int* cur, float* deg) {
    int i = blockIdx.x * 256 + threadIdx.x;
    if (i < 2048) { cnt[i] = 0; cur[i] = 0; deg[i] = 0.f; }
}

__global__ void k_count(const int* __restrict__ ei, const float* __restrict__ ew,
                        int* cnt, float* deg) {
    int e = blockIdx.x * 256 + threadIdx.x;
    if (e < ETOT) {
        int dst; float w;
        if (e < EE) { dst = ei[EE + e]; w = ew[e]; }
        else        { dst = e - EE;     w = 1.f; }
        atomicAdd(&cnt[dst], 1);
        atomicAdd(&deg[dst], w);
    }
}

__global__ __launch_bounds__(1024) void k_scan(const int* __restrict__ cnt, int* off) {
    __shared__ int s[2048];
    int tid = threadIdx.x;
    s[tid]        = (tid        < NN) ? cnt[tid]        : 0;
    s[tid + 1024] = (tid + 1024 < NN) ? cnt[tid + 1024] : 0;
    __syncthreads();
    for (int d = 1; d < 2048; d <<= 1) {
        int idx = (tid + 1) * (d << 1) - 1;
        if (idx < 2048) s[idx] += s[idx - d];
        __syncthreads();
    }
    if (tid == 0) s[2047] = 0;
    __syncthreads();
    for (int d = 1024; d >= 1; d >>= 1) {
        int idx = (tid + 1) * (d << 1) - 1;
        if (idx < 2048) { int t = s[idx - d]; s[idx - d] = s[idx]; s[idx] += t; }
        __syncthreads();
    }
    off[tid] = s[tid];
    off[tid + 1024] = s[tid + 1024];
}

__global__ void k_fill(const int* __restrict__ ei, const float* __restrict__ ew,
                       const float* __restrict__ deg, const int* __restrict__ off,
                       int* cur, int* csr_src, float* csr_nrm) {
    int e = blockIdx.x * 256 + threadIdx.x;
    if (e < ETOT) {
        int src, dst; float w;
        if (e < EE) { src = ei[e]; dst = ei[EE + e]; w = ew[e]; }
        else        { src = dst = e - EE;            w = 1.f; }
        float ds = rsqrtf(fmaxf(deg[src], 1e-12f));
        float dd = rsqrtf(fmaxf(deg[dst], 1e-12f));
        int pos = off[dst] + atomicAdd(&cur[dst], 1);
        csr_src[pos] = src;
        csr_nrm[pos] = ds * w * dd;
    }
}

// ---------------- softmax over causal_weight rows ----------------
__global__ __launch_bounds__(256) void k_softmax(const float* __restrict__ CW,
                                                 float* __restrict__ WC) {
    __shared__ float row[NN];
    __shared__ float red[256];
    int r = blockIdx.x, tid = threadIdx.x;
    const float* in = CW + (size_t)r * NN;
    float mx = -1e30f;
    for (int i = tid; i < NN; i += 256) { float v = in[i]; row[i] = v; mx = fmaxf(mx, v); }
    red[tid] = mx; __syncthreads();
    for (int s = 128; s > 0; s >>= 1) {
        if (tid < s) red[tid] = fmaxf(red[tid], red[tid + s]);
        __syncthreads();
    }
    mx = red[0]; __syncthreads();
    float sm = 0.f;
    for (int i = tid; i < NN; i += 256) { float e = __expf(row[i] - mx); row[i] = e; sm += e; }
    red[tid] = sm; __syncthreads();
    for (int s = 128; s > 0; s >>= 1) {
        if (tid < s) red[tid] += red[tid + s];
        __syncthreads();
    }
    float inv = 1.f / red[0];
    float* out = WC + (size_t)r * NN;
    for (int i = tid; i < NN; i += 256) out[i] = row[i] * inv;
}

// ---------------- lin_in: relu(x_seq @ W^T + b) -> [N,T,H] ----------------
__global__ __launch_bounds__(256) void k_lin_in(const float* __restrict__ XS,
                                                const float* __restrict__ W,
                                                const float* __restrict__ b,
                                                float* __restrict__ OUT) {
    __shared__ float Wt[FIN][HH + 1];
    int tid = threadIdx.x;
    for (int i = tid; i < HH * FIN; i += 256) {
        int o = i >> 5, f = i & 31;
        Wt[f][o] = W[i];
    }
    __syncthreads();
    int n = blockIdx.x;
    int wv = tid >> 6, lane = tid & 63;
    for (int t = wv; t < TT; t += 4) {
        const float4* xr = (const float4*)(XS + ((size_t)t * NN + n) * FIN);
        float acc = b[lane];
#pragma unroll
        for (int q = 0; q < 8; ++q) {
            float4 v = xr[q];
            acc += v.x * Wt[q * 4 + 0][lane] + v.y * Wt[q * 4 + 1][lane]
                 + v.z * Wt[q * 4 + 2][lane] + v.w * Wt[q * 4 + 3][lane];
        }
        OUT[((size_t)n * TT + t) * HH + lane] = fmaxf(acc, 0.f);
    }
}

// ---------------- dense GEMM: XAGG[2000,4096] = WC[2000,2000] @ X[2000,4096] ----------------
__global__ __launch_bounds__(256) void k_gemm(const float* __restrict__ A,
                                              const float* __restrict__ B,
                                              float* __restrict__ Cm) {
    __shared__ alignas(16) float As[16][64];
    __shared__ alignas(16) float Bs[16][64];
    int tid = threadIdx.x;
    int bn = blockIdx.x, bm = blockIdx.y;
    int tx = tid & 15, ty = tid >> 4;
    float acc[4][4] = {};
    int arow = tid >> 2, acq = tid & 3;
    int brow = tid >> 4, bcq = tid & 15;
    int agr = bm * 64 + arow;
    for (int kt = 0; kt < 125; ++kt) {
        float4 av = make_float4(0.f, 0.f, 0.f, 0.f);
        if (agr < NN)
            av = *(const float4*)(A + (size_t)agr * NN + kt * 16 + acq * 4);
        As[acq * 4 + 0][arow] = av.x;
        As[acq * 4 + 1][arow] = av.y;
        As[acq * 4 + 2][arow] = av.z;
        As[acq * 4 + 3][arow] = av.w;
        float4 bv = *(const float4*)(B + (size_t)(kt * 16 + brow) * THL + bn * 64 + bcq * 4);
        *(float4*)&Bs[brow][bcq * 4] = bv;
        __syncthreads();
#pragma unroll
        for (int k = 0; k < 16; ++k) {
            const float4 a = *(const float4*)&As[k][ty * 4];
            const float4 b = *(const float4*)&Bs[k][tx * 4];
            acc[0][0] += a.x * b.x; acc[0][1] += a.x * b.y; acc[0][2] += a.x * b.z; acc[0][3] += a.x * b.w;
            acc[1][0] += a.y * b.x; acc[1][1] += a.y * b.y; acc[1][2] += a.y * b.z; acc[1][3] += a.y * b.w;
            acc[2][0] += a.z * b.x; acc[2][1] += a.z * b.y; acc[2][2] += a.z * b.z; acc[2][3] += a.z * b.w;
            acc[3][0] += a.w * b.x; acc[3][1] += a.w * b.y; acc[3][2] += a.w * b.z; acc[3][3] += a.w * b.w;
        }
        __syncthreads();
    }
#pragma unroll
    for (int i = 0; i < 4; ++i) {
        int gr = bm * 64 + ty * 4 + i;
        if (gr < NN) {
            float4 o = make_float4(acc[i][0], acc[i][1], acc[i][2], acc[i][3]);
            *(float4*)(Cm + (size_t)gr * THL + bn * 64 + tx * 4) = o;
        }
    }
}

// ---------------- fusion: relu([x | x_agg] @ W^T + b) ----------------
__global__ __launch_bounds__(256) void k_fusion(const float* __restrict__ X,
                                                const float* __restrict__ XA,
                                                const float* __restrict__ W,
                                                const float* __restrict__ b,
                                                float* __restrict__ OUT) {
    __shared__ float Wt[2 * HH][HH + 1];
    int tid = threadIdx.x;
    for (int i = tid; i < HH * 2 * HH; i += 256) {
        int o = i >> 7, f = i & 127;
        Wt[f][o] = W[i];
    }
    __syncthreads();
    int n = blockIdx.x;
    int wv = tid >> 6, lane = tid & 63;
    for (int t = wv; t < TT; t += 4) {
        const float4* xr = (const float4*)(X + ((size_t)n * TT + t) * HH);
        const float4* ar = (const float4*)(XA + ((size_t)n * TT + t) * HH);
        float acc = b[lane];
#pragma unroll
        for (int q = 0; q < 16; ++q) {
            float4 v = xr[q];
            acc += v.x * Wt[q * 4 + 0][lane] + v.y * Wt[q * 4 + 1][lane]
                 + v.z * Wt[q * 4 + 2][lane] + v.w * Wt[q * 4 + 3][lane];
        }
#pragma unroll
        for (int q = 0; q < 16; ++q) {
            float4 v = ar[q];
            acc += v.x * Wt[64 + q * 4 + 0][lane] + v.y * Wt[64 + q * 4 + 1][lane]
                 + v.z * Wt[64 + q * 4 + 2][lane] + v.w * Wt[64 + q * 4 + 3][lane];
        }
        OUT[((size_t)n * TT + t) * HH + lane] = fmaxf(acc, 0.f);
    }
}

// ---------------- GCN xw: row @ W^T (no bias) ----------------
__global__ __launch_bounds__(256) void k_xw(const float* __restrict__ IN,
                                            const float* __restrict__ W,
                                            float* __restrict__ OUT) {
    __shared__ float Wt[HH][HH + 1];
    int tid = threadIdx.x;
    for (int i = tid; i < HH * HH; i += 256) {
        int o = i >> 6, f = i & 63;
        Wt[f][o] = W[i];
    }
    __syncthreads();
    int n = blockIdx.x;
    int wv = tid >> 6, lane = tid & 63;
    for (int t = wv; t < TT; t += 4) {
        const float4* xr = (const float4*)(IN + ((size_t)n * TT + t) * HH);
        float acc = 0.f;
#pragma unroll
        for (int q = 0; q < 16; ++q) {
            float4 v = xr[q];
            acc += v.x * Wt[q * 4 + 0][lane] + v.y * Wt[q * 4 + 1][lane]
                 + v.z * Wt[q * 4 + 2][lane] + v.w * Wt[q * 4 + 3][lane];
        }
        OUT[((size_t)n * TT + t) * HH + lane] = acc;
    }
}

// ---------------- GCN aggregate (CSR) + bias + BN + relu ----------------
__global__ __launch_bounds__(256) void k_agg(const float* __restrict__ XW,
                                             const int* __restrict__ off,
                                             const int* __restrict__ csr_src,
                                             const float* __restrict__ csr_nrm,
                                             const float* __restrict__ bias,
                                             const float* __restrict__ g,
                                             const float* __restrict__ bb,
                                             const float* __restrict__ m,
                                             const float* __restrict__ v,
                                             float* __restrict__ OUT) {
    int dst = blockIdx.x, tid = threadIdx.x;
    float acc[16];
#pragma unroll
    for (int k = 0; k < 16; ++k) acc[k] = 0.f;
    int beg = off[dst], end = off[dst + 1];
    for (int e = beg; e < end; ++e) {
        int src = csr_src[e];
        float w = csr_nrm[e];
        const float* xr = XW + (size_t)src * THL;
#pragma unroll
        for (int k = 0; k < 16; ++k) acc[k] += w * xr[tid + k * 256];
    }
    int h = tid & 63;
    float bs = bias[h];
    float scale = rsqrtf(v[h] + EPSBN) * g[h];
    float mean = m[h], beta = bb[h];
    float* orow = OUT + (size_t)dst * THL;
#pragma unroll
    for (int k = 0; k < 16; ++k) {
        float val = (acc[k] + bs - mean) * scale + beta;
        orow[tid + k * 256] = fmaxf(val, 0.f);
    }
}

// ---------------- GRU part A: gi = X @ wih^T + bih for a 16-step chunk ----------------
// grid = NN blocks x 192 threads; thread j holds wih row j in 64 VGPRs.
// GI layout: [n][tc][192], tc chunk-local.
__global__ __launch_bounds__(192) void k_gi(const float* __restrict__ IN,
                                            const float* __restrict__ wih,
                                            const float* __restrict__ bih,
                                            float* __restrict__ GI, int t0) {
    int j = threadIdx.x;
    int n = blockIdx.x;
    float w[64];
    const float4* w4 = (const float4*)(wih + (size_t)j * HH);
#pragma unroll
    for (int q = 0; q < 16; ++q) {
        float4 a = w4[q];
        w[4 * q + 0] = a.x; w[4 * q + 1] = a.y; w[4 * q + 2] = a.z; w[4 * q + 3] = a.w;
    }
    float bias = bih[j];
    float* gout = GI + (size_t)n * (CHT * 192);
    for (int tc = 0; tc < CHT; ++tc) {
        const float4* xr = (const float4*)(IN + ((size_t)n * TT + t0 + tc) * HH);
        float acc = bias;
#pragma unroll
        for (int q = 0; q < 16; ++q) {
            float4 v = xr[q];  // broadcast (uniform address) -> L1 serves all lanes
            acc += v.x * w[4 * q + 0] + v.y * w[4 * q + 1]
                 + v.z * w[4 * q + 2] + v.w * w[4 * q + 3];
        }
        gout[tc * 192 + j] = acc;
    }
}

// ---------------- GRU part B: recurrence, one wave per node ----------------
// lane j owns h[j] and whh rows {j, j+64, j+128} in 192 VGPRs.
// h broadcast via readlane (SGPR operand to FMA): no LDS, no barriers.
__global__ __launch_bounds__(256, 2) void k_rec(const float* __restrict__ GI,
                                                const float* __restrict__ whh,
                                                const float* __restrict__ bhh,
                                                float* __restrict__ hstate,
                                                float* __restrict__ yout,
                                                int t0, int first) {
    int tid = threadIdx.x;
    int wv = tid >> 6, j = tid & 63;
    int n = blockIdx.x * 4 + wv;
    float wr[64], wz[64], wn[64];
    const float4* w4 = (const float4*)whh;
#pragma unroll
    for (int q = 0; q < 16; ++q) {
        float4 a = w4[(size_t)j * 16 + q];
        float4 b = w4[(size_t)(64 + j) * 16 + q];
        float4 c = w4[(size_t)(128 + j) * 16 + q];
        wr[4 * q + 0] = a.x; wr[4 * q + 1] = a.y; wr[4 * q + 2] = a.z; wr[4 * q + 3] = a.w;
        wz[4 * q + 0] = b.x; wz[4 * q + 1] = b.y; wz[4 * q + 2] = b.z; wz[4 * q + 3] = b.w;
        wn[4 * q + 0] = c.x; wn[4 * q + 1] = c.y; wn[4 * q + 2] = c.z; wn[4 * q + 3] = c.w;
    }
    float bhr = bhh[j], bhz = bhh[64 + j], bhn = bhh[128 + j];
    float h = first ? 0.f : hstate[(size_t)n * HH + j];
    const float* gp = GI + (size_t)n * (CHT * 192);
    for (int tc = 0; tc < CHT; ++tc) {
        float gr = gp[tc * 192 + j];
        float gz = gp[tc * 192 + 64 + j];
        float gn = gp[tc * 192 + 128 + j];
        float ar = bhr, az = bhz, an = bhn;
#pragma unroll
        for (int k = 0; k < 64; ++k) {
            float s = __int_as_float(__builtin_amdgcn_readlane(__float_as_int(h), k));
            ar += s * wr[k]; az += s * wz[k]; an += s * wn[k];
        }
        float r = fsigmoid(gr + ar);
        float z = fsigmoid(gz + az);
        float nn2 = tanhf(gn + r * an);
        h = (1.f - z) * nn2 + z * h;
        if (yout) yout[((size_t)n * TT + (t0 + tc)) * HH + j] = h;
    }
    hstate[(size_t)n * HH + j] = h;
}

// ---------------- head: BN + relu + linear + log_softmax ----------------
__global__ __launch_bounds__(256) void k_head(const float* __restrict__ Hf,
                                              const float* __restrict__ g, const float* __restrict__ b,
                                              const float* __restrict__ m, const float* __restrict__ v,
                                              const float* __restrict__ W, const float* __restrict__ wb,
                                              float* __restrict__ out) {
    __shared__ float hb[4][HH];
    __shared__ float lg[4][CC];
    int tid = threadIdx.x;
    int n0 = blockIdx.x * 4;
    int wv = tid >> 6, lane = tid & 63;
    int n = n0 + wv;
    float x = Hf[(size_t)n * HH + lane];
    x = (x - m[lane]) * rsqrtf(v[lane] + EPSBN) * g[lane] + b[lane];
    hb[wv][lane] = fmaxf(x, 0.f);
    __syncthreads();
    if (tid < 4 * CC) {
        int nn = tid / CC, c = tid % CC;
        float acc = wb[c];
        for (int f = 0; f < HH; ++f) acc += hb[nn][f] * W[c * HH + f];
        lg[nn][c] = acc;
    }
    __syncthreads();
    if (tid < 4 * CC) {
        int nn = tid / CC, c = tid % CC;
        float mx = -1e30f;
#pragma unroll
        for (int i = 0; i < CC; ++i) mx = fmaxf(mx, lg[nn][i]);
        float s = 0.f;
#pragma unroll
        for (int i = 0; i < CC; ++i) s += __expf(lg[nn][i] - mx);
        out[(size_t)(n0 + nn) * CC + c] = lg[nn][c] - mx - __logf(s);
    }
}

// ---------------- launch ----------------
extern "C" void kernel_launch(void* const* d_in, const int* in_sizes, int n_in,
                              void* d_out, int out_size, void* d_ws, size_t ws_size,
                              hipStream_t stream) {
    const float* x_seq     = (const float*)d_in[0];
    const int*   edge_idx  = (const int*)d_in[1];
    const float* edge_w    = (const float*)d_in[2];
    const float* causal_w  = (const float*)d_in[3];
    const float* lin_in_w  = (const float*)d_in[4];
    const float* lin_in_b  = (const float*)d_in[5];
    const float* fusion_w  = (const float*)d_in[6];
    const float* fusion_b  = (const float*)d_in[7];
    const float* gcn_w0    = (const float*)d_in[8];
    const float* gcn_b0    = (const float*)d_in[9];
    const float* gcn_w1    = (const float*)d_in[10];
    const float* gcn_b1    = (const float*)d_in[11];
    const float* bn0_g = (const float*)d_in[12], *bn0_b = (const float*)d_in[13];
    const float* bn0_m = (const float*)d_in[14], *bn0_v = (const float*)d_in[15];
    const float* bn1_g = (const float*)d_in[16], *bn1_b = (const float*)d_in[17];
    const float* bn1_m = (const float*)d_in[18], *bn1_v = (const float*)d_in[19];
    const float* wih0 = (const float*)d_in[20], *whh0 = (const float*)d_in[21];
    const float* bih0 = (const float*)d_in[22], *bhh0 = (const float*)d_in[23];
    const float* wih1 = (const float*)d_in[24], *whh1 = (const float*)d_in[25];
    const float* bih1 = (const float*)d_in[26], *bhh1 = (const float*)d_in[27];
    const float* bno_g = (const float*)d_in[28], *bno_b = (const float*)d_in[29];
    const float* bno_m = (const float*)d_in[30], *bno_v = (const float*)d_in[31];
    const float* lout_w = (const float*)d_in[32], *lout_b = (const float*)d_in[33];
    float* out = (float*)d_out;

    float* wsf = (float*)d_ws;
    float* WC  = wsf + OFF_WC;
    float* XA  = wsf + OFF_XA;
    float* XB  = wsf + OFF_XB;
    float* XC  = wsf + OFF_XC;
    float* DEG = wsf + OFF_DEG;
    int* CNT   = (int*)(wsf + OFF_CNT);
    int* CUR   = (int*)(wsf + OFF_CUR);
    int* OFFP  = (int*)(wsf + OFF_OFF);
    int* CSRS  = (int*)(wsf + OFF_CSRS);
    float* CSRN = wsf + OFF_CSRN;
    float* HST  = wsf + OFF_HST;
    float* GIb  = XB;   // GI chunk buffer reuses XB region during the GRU phase

    // CSR + degree build
    k_zero<<<8, 256, 0, stream>>>(CNT, CUR, DEG);
    k_count<<<(ETOT + 255) / 256, 256, 0, stream>>>(edge_idx, edge_w, CNT, DEG);
    k_scan<<<1, 1024, 0, stream>>>(CNT, OFFP);
    k_fill<<<(ETOT + 255) / 256, 256, 0, stream>>>(edge_idx, edge_w, DEG, OFFP, CUR, CSRS, CSRN);

    // causal softmax
    k_softmax<<<NN, 256, 0, stream>>>(causal_w, WC);
    // lin_in -> XA [N,T,H]
    k_lin_in<<<NN, 256, 0, stream>>>(x_seq, lin_in_w, lin_in_b, XA);
    // x_agg = WC @ XA -> XB
    dim3 gg(THL / 64, (NN + 63) / 64);
    k_gemm<<<gg, 256, 0, stream>>>(WC, XA, XB);
    // fusion -> XC
    k_fusion<<<NN, 256, 0, stream>>>(XA, XB, fusion_w, fusion_b, XC);
    // GCN layer 0: XC -> XB (xw) -> XA (agg+bn+relu)
    k_xw<<<NN, 256, 0, stream>>>(XC, gcn_w0, XB);
    k_agg<<<NN, 256, 0, stream>>>(XB, OFFP, CSRS, CSRN, gcn_b0, bn0_g, bn0_b, bn0_m, bn0_v, XA);
    // GCN layer 1: XA -> XB -> XC
    k_xw<<<NN, 256, 0, stream>>>(XA, gcn_w1, XB);
    k_agg<<<NN, 256, 0, stream>>>(XB, OFFP, CSRS, CSRN, gcn_b1, bn1_g, bn1_b, bn1_m, bn1_v, XC);

    // GRU layer 0: input XC -> all-t output H0 in XA (chunked over T)
    for (int c = 0; c < TT / CHT; ++c) {
        k_gi<<<NN, 192, 0, stream>>>(XC, wih0, bih0, GIb, c * CHT);
        k_rec<<<NN / 4, 256, 0, stream>>>(GIb, whh0, bhh0, HST, XA, c * CHT, c == 0);
    }
    // GRU layer 1: input XA (H0) -> final h in HST
    for (int c = 0; c < TT / CHT; ++c) {
        k_gi<<<NN, 192, 0, stream>>>(XA, wih1, bih1, GIb, c * CHT);
        k_rec<<<NN / 4, 256, 0, stream>>>(GIb, whh1, bhh1, HST, (float*)nullptr, c * CHT, c == 0);
    }
    // head
    k_head<<<NN / 4, 256, 0, stream>>>(HST, bno_g, bno_b, bno_m, bno_v, lout_w, lout_b, out);
}

// Round 3
// 1299.459 us; speedup vs baseline: 1.5002x; 1.1777x over previous
//
#include <hip/hip_runtime.h>
#include <hip/hip_bf16.h>
#include <math.h>

#define TT 64
#define NN 2000
#define FIN 32
#define HH 64
#define CC 10
#define EE 32000
#define ETOT 34000   // E + N self loops
#define THL 4096     // T*H
#define EPSBN 1e-5f
#define CHT 16       // GRU time-chunk

// ---------------- workspace layout (float offsets) ----------------
#define OFF_WC   0u          // WCh bf16 [2048][2048] = 8.39 MB (region 16 MB)
#define OFF_XA   4000000u    // 8,192,000  [N,T,H] fp32
#define OFF_XB   12192000u   // 8,192,000  (x_agg fp32; also GI chunk buffer)
#define OFF_XC   20384000u   // 8,192,000  (first: XAh_t bf16 [4096][2048] = 16.78 MB; then fusion out fp32)
#define OFF_DEG  28576000u   // 2048
#define OFF_H1   28578048u   // 128,000 (unused)
#define OFF_CNT  28706048u   // int 2048
#define OFF_CUR  28708096u   // int 2048
#define OFF_OFF  28710144u   // int 2064
#define OFF_CSRS 28712208u   // int 34016
#define OFF_CSRN 28746224u   // float 34016
#define OFF_HST  28780240u   // float 128,000  (GRU h-state)
// total ≈ 28,908,240 floats ≈ 115.6 MB

typedef __attribute__((ext_vector_type(8))) short short8v;
typedef __attribute__((ext_vector_type(4))) float f32x4;

__device__ __forceinline__ float fsigmoid(float x) { return 1.f / (1.f + __expf(-x)); }
__device__ __forceinline__ unsigned short f2bf(float f) {
    __hip_bfloat16 h = __float2bfloat16(f);
    return *reinterpret_cast<unsigned short*>(&h);
}

// ---------------- CSR build ----------------
__global__ void k_zero(int* cnt, int* cur, float* deg) {
    int i = blockIdx.x * 256 + threadIdx.x;
    if (i < 2048) { cnt[i] = 0; cur[i] = 0; deg[i] = 0.f; }
}

__global__ void k_count(const int* __restrict__ ei, const float* __restrict__ ew,
                        int* cnt, float* deg) {
    int e = blockIdx.x * 256 + threadIdx.x;
    if (e < ETOT) {
        int dst; float w;
        if (e < EE) { dst = ei[EE + e]; w = ew[e]; }
        else        { dst = e - EE;     w = 1.f; }
        atomicAdd(&cnt[dst], 1);
        atomicAdd(&deg[dst], w);
    }
}

__global__ __launch_bounds__(1024) void k_scan(const int* __restrict__ cnt, int* off) {
    __shared__ int s[2048];
    int tid = threadIdx.x;
    s[tid]        = (tid        < NN) ? cnt[tid]        : 0;
    s[tid + 1024] = (tid + 1024 < NN) ? cnt[tid + 1024] : 0;
    __syncthreads();
    for (int d = 1; d < 2048; d <<= 1) {
        int idx = (tid + 1) * (d << 1) - 1;
        if (idx < 2048) s[idx] += s[idx - d];
        __syncthreads();
    }
    if (tid == 0) s[2047] = 0;
    __syncthreads();
    for (int d = 1024; d >= 1; d >>= 1) {
        int idx = (tid + 1) * (d << 1) - 1;
        if (idx < 2048) { int t = s[idx - d]; s[idx - d] = s[idx]; s[idx] += t; }
        __syncthreads();
    }
    off[tid] = s[tid];
    off[tid + 1024] = s[tid + 1024];
}

__global__ void k_fill(const int* __restrict__ ei, const float* __restrict__ ew,
                       const float* __restrict__ deg, const int* __restrict__ off,
                       int* cur, int* csr_src, float* csr_nrm) {
    int e = blockIdx.x * 256 + threadIdx.x;
    if (e < ETOT) {
        int src, dst; float w;
        if (e < EE) { src = ei[e]; dst = ei[EE + e]; w = ew[e]; }
        else        { src = dst = e - EE;            w = 1.f; }
        float ds = rsqrtf(fmaxf(deg[src], 1e-12f));
        float dd = rsqrtf(fmaxf(deg[dst], 1e-12f));
        int pos = off[dst] + atomicAdd(&cur[dst], 1);
        csr_src[pos] = src;
        csr_nrm[pos] = ds * w * dd;
    }
}

// ---------------- softmax over causal_weight rows -> bf16 WCh [2048 stride] ----------------
__global__ __launch_bounds__(256) void k_softmax(const float* __restrict__ CW,
                                                 unsigned short* __restrict__ WCH) {
    __shared__ float row[NN];
    __shared__ float red[256];
    int r = blockIdx.x, tid = threadIdx.x;
    const float* in = CW + (size_t)r * NN;
    float mx = -1e30f;
    for (int i = tid; i < NN; i += 256) { float v = in[i]; row[i] = v; mx = fmaxf(mx, v); }
    red[tid] = mx; __syncthreads();
    for (int s = 128; s > 0; s >>= 1) {
        if (tid < s) red[tid] = fmaxf(red[tid], red[tid + s]);
        __syncthreads();
    }
    mx = red[0]; __syncthreads();
    float sm = 0.f;
    for (int i = tid; i < NN; i += 256) { float e = __expf(row[i] - mx); row[i] = e; sm += e; }
    red[tid] = sm; __syncthreads();
    for (int s = 128; s > 0; s >>= 1) {
        if (tid < s) red[tid] += red[tid + s];
        __syncthreads();
    }
    float inv = 1.f / red[0];
    unsigned short* out = WCH + (size_t)r * 2048;
    for (int i = tid; i < 2048; i += 256)
        out[i] = (i < NN) ? f2bf(row[i] * inv) : (unsigned short)0;
}

// ---------------- lin_in: relu(x_seq @ W^T + b) -> [N,T,H] fp32 ----------------
__global__ __launch_bounds__(256) void k_lin_in(const float* __restrict__ XS,
                                                const float* __restrict__ W,
                                                const float* __restrict__ b,
                                                float* __restrict__ OUT) {
    __shared__ float Wt[FIN][HH + 1];
    int tid = threadIdx.x;
    for (int i = tid; i < HH * FIN; i += 256) {
        int o = i >> 5, f = i & 31;
        Wt[f][o] = W[i];
    }
    __syncthreads();
    int n = blockIdx.x;
    int wv = tid >> 6, lane = tid & 63;
    for (int t = wv; t < TT; t += 4) {
        const float4* xr = (const float4*)(XS + ((size_t)t * NN + n) * FIN);
        float acc = b[lane];
#pragma unroll
        for (int q = 0; q < 8; ++q) {
            float4 v = xr[q];
            acc += v.x * Wt[q * 4 + 0][lane] + v.y * Wt[q * 4 + 1][lane]
                 + v.z * Wt[q * 4 + 2][lane] + v.w * Wt[q * 4 + 3][lane];
        }
        OUT[((size_t)n * TT + t) * HH + lane] = fmaxf(acc, 0.f);
    }
}

// ---------------- transpose + bf16 cast: XA [2048(k),4096(c)] -> XAh_t [4096(c),2048(k)] ----------------
__global__ __launch_bounds__(256) void k_tr(const float* __restrict__ X,
                                            unsigned short* __restrict__ XT) {
    __shared__ unsigned short tile[64][65];
    int cb = blockIdx.x * 64;   // c dim
    int kb = blockIdx.y * 64;   // k dim
    int tid = threadIdx.x;
    int r = tid >> 2, cq = tid & 3;
    const float4* src = (const float4*)(X + (size_t)(kb + r) * THL + cb + cq * 16);
#pragma unroll
    for (int j = 0; j < 4; ++j) {
        float4 v = src[j];
        tile[cq * 16 + j * 4 + 0][r] = f2bf(v.x);
        tile[cq * 16 + j * 4 + 1][r] = f2bf(v.y);
        tile[cq * 16 + j * 4 + 2][r] = f2bf(v.z);
        tile[cq * 16 + j * 4 + 3][r] = f2bf(v.w);
    }
    __syncthreads();
    int cl = tid >> 2, kq = tid & 3;
    unsigned short tmp[16];
#pragma unroll
    for (int j = 0; j < 16; ++j) tmp[j] = tile[cl][kq * 16 + j];
    unsigned short* dst = XT + (size_t)(cb + cl) * 2048 + kb + kq * 16;
    *(uint4*)dst = *(uint4*)tmp;
    *(uint4*)(dst + 8) = *(uint4*)(tmp + 8);
}

// ---------------- bf16 MFMA GEMM: C[2000,4096] = WCh[2048,2048] @ X (via XAh_t[4096,2048]) ----------------
__global__ __launch_bounds__(256) void k_gemm_bf(const unsigned short* __restrict__ A,
                                                 const unsigned short* __restrict__ B,
                                                 float* __restrict__ C) {
    __shared__ unsigned short As[128][72];   // stride 144B -> banks 4r mod 32 (2-way, free)
    __shared__ unsigned short Bs[128][72];
    int tid = threadIdx.x;
    int mb = blockIdx.y * 128, nb = blockIdx.x * 128;
    int w = tid >> 6, lane = tid & 63;
    int wr = w >> 1, wc = w & 1;
    int l15 = lane & 15, l4 = lane >> 4;
    f32x4 acc[4][4] = {};
    int r = tid >> 1, hf = tid & 1;
    const uint4* ga = (const uint4*)(A + (size_t)(mb + r) * 2048 + hf * 32);
    const uint4* gb = (const uint4*)(B + (size_t)(nb + r) * 2048 + hf * 32);
    for (int kt = 0; kt < 32; ++kt) {
        uint4 va[4], vb[4];
#pragma unroll
        for (int j = 0; j < 4; ++j) { va[j] = ga[j]; vb[j] = gb[j]; }
        ga += 8; gb += 8;   // advance K by 64 bf16
        __syncthreads();    // previous iteration's frag reads done
#pragma unroll
        for (int j = 0; j < 4; ++j) {
            *(uint4*)&As[r][hf * 32 + j * 8] = va[j];
            *(uint4*)&Bs[r][hf * 32 + j * 8] = vb[j];
        }
        __syncthreads();
#pragma unroll
        for (int kk = 0; kk < 2; ++kk) {
            short8v af[4], bfr[4];
#pragma unroll
            for (int f = 0; f < 4; ++f) {
                af[f]  = *(const short8v*)&As[wr * 64 + f * 16 + l15][kk * 32 + l4 * 8];
                bfr[f] = *(const short8v*)&Bs[wc * 64 + f * 16 + l15][kk * 32 + l4 * 8];
            }
#pragma unroll
            for (int fm = 0; fm < 4; ++fm)
#pragma unroll
                for (int fn = 0; fn < 4; ++fn)
                    acc[fm][fn] = __builtin_amdgcn_mfma_f32_16x16x32_bf16(af[fm], bfr[fn], acc[fm][fn], 0, 0, 0);
        }
    }
#pragma unroll
    for (int fm = 0; fm < 4; ++fm) {
        int gr0 = mb + wr * 64 + fm * 16 + l4 * 4;
#pragma unroll
        for (int rr = 0; rr < 4; ++rr) {
            int grow = gr0 + rr;
            if (grow < NN) {
#pragma unroll
                for (int fn = 0; fn < 4; ++fn) {
                    int gcol = nb + wc * 64 + fn * 16 + l15;
                    C[(size_t)grow * THL + gcol] = acc[fm][fn][rr];
                }
            }
        }
    }
}

// ---------------- fusion: relu([x | x_agg] @ W^T + b) ----------------
__global__ __launch_bounds__(256) void k_fusion(const float* __restrict__ X,
                                                const float* __restrict__ XA,
                                                const float* __restrict__ W,
                                                const float* __restrict__ b,
                                                float* __restrict__ OUT) {
    __shared__ float Wt[2 * HH][HH + 1];
    int tid = threadIdx.x;
    for (int i = tid; i < HH * 2 * HH; i += 256) {
        int o = i >> 7, f = i & 127;
        Wt[f][o] = W[i];
    }
    __syncthreads();
    int n = blockIdx.x;
    int wv = tid >> 6, lane = tid & 63;
    for (int t = wv; t < TT; t += 4) {
        const float4* xr = (const float4*)(X + ((size_t)n * TT + t) * HH);
        const float4* ar = (const float4*)(XA + ((size_t)n * TT + t) * HH);
        float acc = b[lane];
#pragma unroll
        for (int q = 0; q < 16; ++q) {
            float4 v = xr[q];
            acc += v.x * Wt[q * 4 + 0][lane] + v.y * Wt[q * 4 + 1][lane]
                 + v.z * Wt[q * 4 + 2][lane] + v.w * Wt[q * 4 + 3][lane];
        }
#pragma unroll
        for (int q = 0; q < 16; ++q) {
            float4 v = ar[q];
            acc += v.x * Wt[64 + q * 4 + 0][lane] + v.y * Wt[64 + q * 4 + 1][lane]
                 + v.z * Wt[64 + q * 4 + 2][lane] + v.w * Wt[64 + q * 4 + 3][lane];
        }
        OUT[((size_t)n * TT + t) * HH + lane] = fmaxf(acc, 0.f);
    }
}

// ---------------- GCN xw: row @ W^T (no bias) ----------------
__global__ __launch_bounds__(256) void k_xw(const float* __restrict__ IN,
                                            const float* __restrict__ W,
                                            float* __restrict__ OUT) {
    __shared__ float Wt[HH][HH + 1];
    int tid = threadIdx.x;
    for (int i = tid; i < HH * HH; i += 256) {
        int o = i >> 6, f = i & 63;
        Wt[f][o] = W[i];
    }
    __syncthreads();
    int n = blockIdx.x;
    int wv = tid >> 6, lane = tid & 63;
    for (int t = wv; t < TT; t += 4) {
        const float4* xr = (const float4*)(IN + ((size_t)n * TT + t) * HH);
        float acc = 0.f;
#pragma unroll
        for (int q = 0; q < 16; ++q) {
            float4 v = xr[q];
            acc += v.x * Wt[q * 4 + 0][lane] + v.y * Wt[q * 4 + 1][lane]
                 + v.z * Wt[q * 4 + 2][lane] + v.w * Wt[q * 4 + 3][lane];
        }
        OUT[((size_t)n * TT + t) * HH + lane] = acc;
    }
}

// ---------------- GCN aggregate (CSR) + bias + BN + relu ----------------
__global__ __launch_bounds__(256) void k_agg(const float* __restrict__ XW,
                                             const int* __restrict__ off,
                                             const int* __restrict__ csr_src,
                                             const float* __restrict__ csr_nrm,
                                             const float* __restrict__ bias,
                                             const float* __restrict__ g,
                                             const float* __restrict__ bb,
                                             const float* __restrict__ m,
                                             const float* __restrict__ v,
                                             float* __restrict__ OUT) {
    int dst = blockIdx.x, tid = threadIdx.x;
    float acc[16];
#pragma unroll
    for (int k = 0; k < 16; ++k) acc[k] = 0.f;
    int beg = off[dst], end = off[dst + 1];
    for (int e = beg; e < end; ++e) {
        int src = csr_src[e];
        float w = csr_nrm[e];
        const float* xr = XW + (size_t)src * THL;
#pragma unroll
        for (int k = 0; k < 16; ++k) acc[k] += w * xr[tid + k * 256];
    }
    int h = tid & 63;
    float bs = bias[h];
    float scale = rsqrtf(v[h] + EPSBN) * g[h];
    float mean = m[h], beta = bb[h];
    float* orow = OUT + (size_t)dst * THL;
#pragma unroll
    for (int k = 0; k < 16; ++k) {
        float val = (acc[k] + bs - mean) * scale + beta;
        orow[tid + k * 256] = fmaxf(val, 0.f);
    }
}

// ---------------- GRU part A: gi = X @ wih^T + bih for a 16-step chunk ----------------
__global__ __launch_bounds__(192) void k_gi(const float* __restrict__ IN,
                                            const float* __restrict__ wih,
                                            const float* __restrict__ bih,
                                            float* __restrict__ GI, int t0) {
    int j = threadIdx.x;
    int n = blockIdx.x;
    float w[64];
    const float4* w4 = (const float4*)(wih + (size_t)j * HH);
#pragma unroll
    for (int q = 0; q < 16; ++q) {
        float4 a = w4[q];
        w[4 * q + 0] = a.x; w[4 * q + 1] = a.y; w[4 * q + 2] = a.z; w[4 * q + 3] = a.w;
    }
    float bias = bih[j];
    float* gout = GI + (size_t)n * (CHT * 192);
    for (int tc = 0; tc < CHT; ++tc) {
        const float4* xr = (const float4*)(IN + ((size_t)n * TT + t0 + tc) * HH);
        float acc = bias;
#pragma unroll
        for (int q = 0; q < 16; ++q) {
            float4 v = xr[q];
            acc += v.x * w[4 * q + 0] + v.y * w[4 * q + 1]
                 + v.z * w[4 * q + 2] + v.w * w[4 * q + 3];
        }
        gout[tc * 192 + j] = acc;
    }
}

// ---------------- GRU part B: recurrence, one wave per node ----------------
__global__ __launch_bounds__(256, 2) void k_rec(const float* __restrict__ GI,
                                                const float* __restrict__ whh,
                                                const float* __restrict__ bhh,
                                                float* __restrict__ hstate,
                                                float* __restrict__ yout,
                                                int t0, int first) {
    int tid = threadIdx.x;
    int wv = tid >> 6, j = tid & 63;
    int n = blockIdx.x * 4 + wv;
    float wr[64], wz[64], wn[64];
    const float4* w4 = (const float4*)whh;
#pragma unroll
    for (int q = 0; q < 16; ++q) {
        float4 a = w4[(size_t)j * 16 + q];
        float4 b = w4[(size_t)(64 + j) * 16 + q];
        float4 c = w4[(size_t)(128 + j) * 16 + q];
        wr[4 * q + 0] = a.x; wr[4 * q + 1] = a.y; wr[4 * q + 2] = a.z; wr[4 * q + 3] = a.w;
        wz[4 * q + 0] = b.x; wz[4 * q + 1] = b.y; wz[4 * q + 2] = b.z; wz[4 * q + 3] = b.w;
        wn[4 * q + 0] = c.x; wn[4 * q + 1] = c.y; wn[4 * q + 2] = c.z; wn[4 * q + 3] = c.w;
    }
    float bhr = bhh[j], bhz = bhh[64 + j], bhn = bhh[128 + j];
    float h = first ? 0.f : hstate[(size_t)n * HH + j];
    const float* gp = GI + (size_t)n * (CHT * 192);
    for (int tc = 0; tc < CHT; ++tc) {
        float gr = gp[tc * 192 + j];
        float gz = gp[tc * 192 + 64 + j];
        float gn = gp[tc * 192 + 128 + j];
        float ar = bhr, az = bhz, an = bhn;
#pragma unroll
        for (int k = 0; k < 64; ++k) {
            float s = __int_as_float(__builtin_amdgcn_readlane(__float_as_int(h), k));
            ar += s * wr[k]; az += s * wz[k]; an += s * wn[k];
        }
        float r = fsigmoid(gr + ar);
        float z = fsigmoid(gz + az);
        float nn2 = tanhf(gn + r * an);
        h = (1.f - z) * nn2 + z * h;
        if (yout) yout[((size_t)n * TT + (t0 + tc)) * HH + j] = h;
    }
    hstate[(size_t)n * HH + j] = h;
}

// ---------------- head: BN + relu + linear + log_softmax ----------------
__global__ __launch_bounds__(256) void k_head(const float* __restrict__ Hf,
                                              const float* __restrict__ g, const float* __restrict__ b,
                                              const float* __restrict__ m, const float* __restrict__ v,
                                              const float* __restrict__ W, const float* __restrict__ wb,
                                              float* __restrict__ out) {
    __shared__ float hb[4][HH];
    __shared__ float lg[4][CC];
    int tid = threadIdx.x;
    int n0 = blockIdx.x * 4;
    int wv = tid >> 6, lane = tid & 63;
    int n = n0 + wv;
    float x = Hf[(size_t)n * HH + lane];
    x = (x - m[lane]) * rsqrtf(v[lane] + EPSBN) * g[lane] + b[lane];
    hb[wv][lane] = fmaxf(x, 0.f);
    __syncthreads();
    if (tid < 4 * CC) {
        int nn = tid / CC, c = tid % CC;
        float acc = wb[c];
        for (int f = 0; f < HH; ++f) acc += hb[nn][f] * W[c * HH + f];
        lg[nn][c] = acc;
    }
    __syncthreads();
    if (tid < 4 * CC) {
        int nn = tid / CC, c = tid % CC;
        float mx = -1e30f;
#pragma unroll
        for (int i = 0; i < CC; ++i) mx = fmaxf(mx, lg[nn][i]);
        float s = 0.f;
#pragma unroll
        for (int i = 0; i < CC; ++i) s += __expf(lg[nn][i] - mx);
        out[(size_t)(n0 + nn) * CC + c] = lg[nn][c] - mx - __logf(s);
    }
}

// ---------------- launch ----------------
extern "C" void kernel_launch(void* const* d_in, const int* in_sizes, int n_in,
                              void* d_out, int out_size, void* d_ws, size_t ws_size,
                              hipStream_t stream) {
    const float* x_seq     = (const float*)d_in[0];
    const int*   edge_idx  = (const int*)d_in[1];
    const float* edge_w    = (const float*)d_in[2];
    const float* causal_w  = (const float*)d_in[3];
    const float* lin_in_w  = (const float*)d_in[4];
    const float* lin_in_b  = (const float*)d_in[5];
    const float* fusion_w  = (const float*)d_in[6];
    const float* fusion_b  = (const float*)d_in[7];
    const float* gcn_w0    = (const float*)d_in[8];
    const float* gcn_b0    = (const float*)d_in[9];
    const float* gcn_w1    = (const float*)d_in[10];
    const float* gcn_b1    = (const float*)d_in[11];
    const float* bn0_g = (const float*)d_in[12], *bn0_b = (const float*)d_in[13];
    const float* bn0_m = (const float*)d_in[14], *bn0_v = (const float*)d_in[15];
    const float* bn1_g = (const float*)d_in[16], *bn1_b = (const float*)d_in[17];
    const float* bn1_m = (const float*)d_in[18], *bn1_v = (const float*)d_in[19];
    const float* wih0 = (const float*)d_in[20], *whh0 = (const float*)d_in[21];
    const float* bih0 = (const float*)d_in[22], *bhh0 = (const float*)d_in[23];
    const float* wih1 = (const float*)d_in[24], *whh1 = (const float*)d_in[25];
    const float* bih1 = (const float*)d_in[26], *bhh1 = (const float*)d_in[27];
    const float* bno_g = (const float*)d_in[28], *bno_b = (const float*)d_in[29];
    const float* bno_m = (const float*)d_in[30], *bno_v = (const float*)d_in[31];
    const float* lout_w = (const float*)d_in[32], *lout_b = (const float*)d_in[33];
    float* out = (float*)d_out;

    float* wsf = (float*)d_ws;
    unsigned short* WCH = (unsigned short*)(wsf + OFF_WC);   // bf16 [2048][2048]
    float* XA  = wsf + OFF_XA;
    float* XB  = wsf + OFF_XB;
    float* XC  = wsf + OFF_XC;
    unsigned short* XAT = (unsigned short*)(wsf + OFF_XC);   // bf16 [4096][2048] (pre-fusion)
    float* DEG = wsf + OFF_DEG;
    int* CNT   = (int*)(wsf + OFF_CNT);
    int* CUR   = (int*)(wsf + OFF_CUR);
    int* OFFP  = (int*)(wsf + OFF_OFF);
    int* CSRS  = (int*)(wsf + OFF_CSRS);
    float* CSRN = wsf + OFF_CSRN;
    float* HST  = wsf + OFF_HST;
    float* GIb  = XB;   // GI chunk buffer reuses XB region during the GRU phase

    // CSR + degree build
    k_zero<<<8, 256, 0, stream>>>(CNT, CUR, DEG);
    k_count<<<(ETOT + 255) / 256, 256, 0, stream>>>(edge_idx, edge_w, CNT, DEG);
    k_scan<<<1, 1024, 0, stream>>>(CNT, OFFP);
    k_fill<<<(ETOT + 255) / 256, 256, 0, stream>>>(edge_idx, edge_w, DEG, OFFP, CUR, CSRS, CSRN);

    // zero WCh (pad rows deterministic)
    hipMemsetAsync(WCH, 0, (size_t)2048 * 2048 * 2, stream);
    // causal softmax -> bf16 WCh
    k_softmax<<<NN, 256, 0, stream>>>(causal_w, WCH);
    // lin_in -> XA [N,T,H] fp32
    k_lin_in<<<NN, 256, 0, stream>>>(x_seq, lin_in_w, lin_in_b, XA);
    // transpose+cast: XA -> XAh_t bf16 [4096][2048]
    dim3 tg(THL / 64, 2048 / 64);
    k_tr<<<tg, 256, 0, stream>>>(XA, XAT);
    // x_agg = WCh @ X (MFMA bf16) -> XB fp32
    dim3 gg(THL / 128, 2048 / 128);
    k_gemm_bf<<<gg, 256, 0, stream>>>(WCH, XAT, XB);
    // fusion -> XC (overwrites XAT region; gemm already consumed it)
    k_fusion<<<NN, 256, 0, stream>>>(XA, XB, fusion_w, fusion_b, XC);
    // GCN layer 0: XC -> XB (xw) -> XA (agg+bn+relu)
    k_xw<<<NN, 256, 0, stream>>>(XC, gcn_w0, XB);
    k_agg<<<NN, 256, 0, stream>>>(XB, OFFP, CSRS, CSRN, gcn_b0, bn0_g, bn0_b, bn0_m, bn0_v, XA);
    // GCN layer 1: XA -> XB -> XC
    k_xw<<<NN, 256, 0, stream>>>(XA, gcn_w1, XB);
    k_agg<<<NN, 256, 0, stream>>>(XB, OFFP, CSRS, CSRN, gcn_b1, bn1_g, bn1_b, bn1_m, bn1_v, XC);

    // GRU layer 0: input XC -> all-t output H0 in XA (chunked over T)
    for (int c = 0; c < TT / CHT; ++c) {
        k_gi<<<NN, 192, 0, stream>>>(XC, wih0, bih0, GIb, c * CHT);
        k_rec<<<NN / 4, 256, 0, stream>>>(GIb, whh0, bhh0, HST, XA, c * CHT, c == 0);
    }
    // GRU layer 1: input XA (H0) -> final h in HST
    for (int c = 0; c < TT / CHT; ++c) {
        k_gi<<<NN, 192, 0, stream>>>(XA, wih1, bih1, GIb, c * CHT);
        k_rec<<<NN / 4, 256, 0, stream>>>(GIb, whh1, bhh1, HST, (float*)nullptr, c * CHT, c == 0);
    }
    // head
    k_head<<<NN / 4, 256, 0, stream>>>(HST, bno_g, bno_b, bno_m, bno_v, lout_w, lout_b, out);
}

// Round 4
// 1273.175 us; speedup vs baseline: 1.5311x; 1.0206x over previous
//
#include <hip/hip_runtime.h>
#include <hip/hip_bf16.h>
#include <math.h>

#define TT 64
#define NN 2000
#define FIN 32
#define HH 64
#define CC 10
#define EE 32000
#define ETOT 34000   // E + N self loops
#define THL 4096     // T*H
#define EPSBN 1e-5f
#define CHT 16       // GRU time-chunk

// ---------------- workspace layout (float offsets) ----------------
#define OFF_WC   0u          // WCh bf16 [2048][2048] = 8.39 MB (region 16 MB)
#define OFF_XA   4000000u    // 8,192,000  [N,T,H] fp32
#define OFF_XB   12192000u   // 8,192,000  (x_agg fp32; also GI chunk buffer)
#define OFF_XC   20384000u   // 8,192,000  (first: XAh_t bf16 [4096][2048]; then fusion out fp32)
#define OFF_DEG  28576000u   // 2048
#define OFF_H1   28578048u   // 128,000 (unused)
#define OFF_CNT  28706048u   // int 2048
#define OFF_CUR  28708096u   // int 2048
#define OFF_OFF  28710144u   // int 2064
#define OFF_CSRS 28712208u   // int 34016
#define OFF_CSRN 28746224u   // float 34016
#define OFF_HST  28780240u   // float 128,000  (GRU h-state)
// total ≈ 28,908,240 floats ≈ 115.6 MB

typedef __attribute__((ext_vector_type(8))) short short8v;
typedef __attribute__((ext_vector_type(4))) float f32x4;

__device__ __forceinline__ float fsigmoid(float x) { return 1.f / (1.f + __expf(-x)); }
__device__ __forceinline__ unsigned short f2bf(float f) {
    __hip_bfloat16 h = __float2bfloat16(f);
    return *reinterpret_cast<unsigned short*>(&h);
}

// ---------------- CSR build ----------------
__global__ void k_zero(int* cnt, int* cur, float* deg) {
    int i = blockIdx.x * 256 + threadIdx.x;
    if (i < 2048) { cnt[i] = 0; cur[i] = 0; deg[i] = 0.f; }
}

__global__ void k_count(const int* __restrict__ ei, const float* __restrict__ ew,
                        int* cnt, float* deg) {
    int e = blockIdx.x * 256 + threadIdx.x;
    if (e < ETOT) {
        int dst; float w;
        if (e < EE) { dst = ei[EE + e]; w = ew[e]; }
        else        { dst = e - EE;     w = 1.f; }
        atomicAdd(&cnt[dst], 1);
        atomicAdd(&deg[dst], w);
    }
}

__global__ __launch_bounds__(1024) void k_scan(const int* __restrict__ cnt, int* off) {
    __shared__ int s[2048];
    int tid = threadIdx.x;
    s[tid]        = (tid        < NN) ? cnt[tid]        : 0;
    s[tid + 1024] = (tid + 1024 < NN) ? cnt[tid + 1024] : 0;
    __syncthreads();
    for (int d = 1; d < 2048; d <<= 1) {
        int idx = (tid + 1) * (d << 1) - 1;
        if (idx < 2048) s[idx] += s[idx - d];
        __syncthreads();
    }
    if (tid == 0) s[2047] = 0;
    __syncthreads();
    for (int d = 1024; d >= 1; d >>= 1) {
        int idx = (tid + 1) * (d << 1) - 1;
        if (idx < 2048) { int t = s[idx - d]; s[idx - d] = s[idx]; s[idx] += t; }
        __syncthreads();
    }
    off[tid] = s[tid];
    off[tid + 1024] = s[tid + 1024];
}

__global__ void k_fill(const int* __restrict__ ei, const float* __restrict__ ew,
                       const float* __restrict__ deg, const int* __restrict__ off,
                       int* cur, int* csr_src, float* csr_nrm) {
    int e = blockIdx.x * 256 + threadIdx.x;
    if (e < ETOT) {
        int src, dst; float w;
        if (e < EE) { src = ei[e]; dst = ei[EE + e]; w = ew[e]; }
        else        { src = dst = e - EE;            w = 1.f; }
        float ds = rsqrtf(fmaxf(deg[src], 1e-12f));
        float dd = rsqrtf(fmaxf(deg[dst], 1e-12f));
        int pos = off[dst] + atomicAdd(&cur[dst], 1);
        csr_src[pos] = src;
        csr_nrm[pos] = ds * w * dd;
    }
}

// ---------------- softmax over causal_weight rows -> bf16 WCh [2048 stride] ----------------
__global__ __launch_bounds__(256) void k_softmax(const float* __restrict__ CW,
                                                 unsigned short* __restrict__ WCH) {
    __shared__ float row[NN];
    __shared__ float red[256];
    int r = blockIdx.x, tid = threadIdx.x;
    const float* in = CW + (size_t)r * NN;
    float mx = -1e30f;
    for (int i = tid; i < NN; i += 256) { float v = in[i]; row[i] = v; mx = fmaxf(mx, v); }
    red[tid] = mx; __syncthreads();
    for (int s = 128; s > 0; s >>= 1) {
        if (tid < s) red[tid] = fmaxf(red[tid], red[tid + s]);
        __syncthreads();
    }
    mx = red[0]; __syncthreads();
    float sm = 0.f;
    for (int i = tid; i < NN; i += 256) { float e = __expf(row[i] - mx); row[i] = e; sm += e; }
    red[tid] = sm; __syncthreads();
    for (int s = 128; s > 0; s >>= 1) {
        if (tid < s) red[tid] += red[tid + s];
        __syncthreads();
    }
    float inv = 1.f / red[0];
    unsigned short* out = WCH + (size_t)r * 2048;
    for (int i = tid; i < 2048; i += 256)
        out[i] = (i < NN) ? f2bf(row[i] * inv) : (unsigned short)0;
}

// ---------------- lin_in: relu(x_seq @ W^T + b) -> [N,T,H] fp32 ----------------
__global__ __launch_bounds__(256) void k_lin_in(const float* __restrict__ XS,
                                                const float* __restrict__ W,
                                                const float* __restrict__ b,
                                                float* __restrict__ OUT) {
    // register-weight pattern: lane j owns output neuron j (32 weights in VGPR)
    int tid = threadIdx.x;
    int slot = tid >> 6, j = tid & 63;
    int n = blockIdx.x;
    float w[FIN];
    const float4* w4 = (const float4*)(W + (size_t)j * FIN);
#pragma unroll
    for (int q = 0; q < 8; ++q) {
        float4 a = w4[q];
        w[4 * q + 0] = a.x; w[4 * q + 1] = a.y; w[4 * q + 2] = a.z; w[4 * q + 3] = a.w;
    }
    float bj = b[j];
    for (int t = slot; t < TT; t += 4) {
        const float4* xr = (const float4*)(XS + ((size_t)t * NN + n) * FIN);
        float acc = bj;
#pragma unroll
        for (int q = 0; q < 8; ++q) {
            float4 v = xr[q];   // wave-uniform -> scalar loads
            acc += v.x * w[4 * q + 0] + v.y * w[4 * q + 1]
                 + v.z * w[4 * q + 2] + v.w * w[4 * q + 3];
        }
        OUT[((size_t)n * TT + t) * HH + j] = fmaxf(acc, 0.f);
    }
}

// ---------------- transpose + bf16 cast: XA [2048(k),4096(c)] -> XAh_t [4096(c),2048(k)] ----------------
__global__ __launch_bounds__(256) void k_tr(const float* __restrict__ X,
                                            unsigned short* __restrict__ XT) {
    __shared__ unsigned short tile[64][65];
    int cb = blockIdx.x * 64;   // c dim
    int kb = blockIdx.y * 64;   // k dim
    int tid = threadIdx.x;
    int r = tid >> 2, cq = tid & 3;
    const float4* src = (const float4*)(X + (size_t)(kb + r) * THL + cb + cq * 16);
#pragma unroll
    for (int j = 0; j < 4; ++j) {
        float4 v = src[j];
        tile[cq * 16 + j * 4 + 0][r] = f2bf(v.x);
        tile[cq * 16 + j * 4 + 1][r] = f2bf(v.y);
        tile[cq * 16 + j * 4 + 2][r] = f2bf(v.z);
        tile[cq * 16 + j * 4 + 3][r] = f2bf(v.w);
    }
    __syncthreads();
    int cl = tid >> 2, kq = tid & 3;
    unsigned short tmp[16];
#pragma unroll
    for (int j = 0; j < 16; ++j) tmp[j] = tile[cl][kq * 16 + j];
    unsigned short* dst = XT + (size_t)(cb + cl) * 2048 + kb + kq * 16;
    *(uint4*)dst = *(uint4*)tmp;
    *(uint4*)(dst + 8) = *(uint4*)(tmp + 8);
}

// ---------------- bf16 MFMA GEMM: C[2000,4096] = WCh[2048,2048] @ X (via XAh_t[4096,2048]) ----------------
__global__ __launch_bounds__(256) void k_gemm_bf(const unsigned short* __restrict__ A,
                                                 const unsigned short* __restrict__ B,
                                                 float* __restrict__ C) {
    __shared__ unsigned short As[128][72];   // stride 144B -> 2-way bank alias (free)
    __shared__ unsigned short Bs[128][72];
    int tid = threadIdx.x;
    int mb = blockIdx.y * 128, nb = blockIdx.x * 128;
    int w = tid >> 6, lane = tid & 63;
    int wr = w >> 1, wc = w & 1;
    int l15 = lane & 15, l4 = lane >> 4;
    f32x4 acc[4][4] = {};
    int r = tid >> 1, hf = tid & 1;
    const uint4* ga = (const uint4*)(A + (size_t)(mb + r) * 2048 + hf * 32);
    const uint4* gb = (const uint4*)(B + (size_t)(nb + r) * 2048 + hf * 32);
    for (int kt = 0; kt < 32; ++kt) {
        uint4 va[4], vb[4];
#pragma unroll
        for (int j = 0; j < 4; ++j) { va[j] = ga[j]; vb[j] = gb[j]; }
        ga += 8; gb += 8;   // advance K by 64 bf16
        __syncthreads();    // previous iteration's frag reads done
#pragma unroll
        for (int j = 0; j < 4; ++j) {
            *(uint4*)&As[r][hf * 32 + j * 8] = va[j];
            *(uint4*)&Bs[r][hf * 32 + j * 8] = vb[j];
        }
        __syncthreads();
#pragma unroll
        for (int kk = 0; kk < 2; ++kk) {
            short8v af[4], bfr[4];
#pragma unroll
            for (int f = 0; f < 4; ++f) {
                af[f]  = *(const short8v*)&As[wr * 64 + f * 16 + l15][kk * 32 + l4 * 8];
                bfr[f] = *(const short8v*)&Bs[wc * 64 + f * 16 + l15][kk * 32 + l4 * 8];
            }
#pragma unroll
            for (int fm = 0; fm < 4; ++fm)
#pragma unroll
                for (int fn = 0; fn < 4; ++fn)
                    acc[fm][fn] = __builtin_amdgcn_mfma_f32_16x16x32_bf16(af[fm], bfr[fn], acc[fm][fn], 0, 0, 0);
        }
    }
#pragma unroll
    for (int fm = 0; fm < 4; ++fm) {
        int gr0 = mb + wr * 64 + fm * 16 + l4 * 4;
#pragma unroll
        for (int rr = 0; rr < 4; ++rr) {
            int grow = gr0 + rr;
            if (grow < NN) {
#pragma unroll
                for (int fn = 0; fn < 4; ++fn) {
                    int gcol = nb + wc * 64 + fn * 16 + l15;
                    C[(size_t)grow * THL + gcol] = acc[fm][fn][rr];
                }
            }
        }
    }
}

// ---------------- fusion: relu([x | x_agg] @ W^T + b), register-weight ----------------
__global__ __launch_bounds__(256) void k_fusion(const float* __restrict__ X,
                                                const float* __restrict__ XA,
                                                const float* __restrict__ W,
                                                const float* __restrict__ b,
                                                float* __restrict__ OUT) {
    int tid = threadIdx.x;
    int slot = tid >> 6, j = tid & 63;
    int n = blockIdx.x;
    float w[2 * HH];
    const float4* w4 = (const float4*)(W + (size_t)j * (2 * HH));
#pragma unroll
    for (int q = 0; q < 32; ++q) {
        float4 a = w4[q];
        w[4 * q + 0] = a.x; w[4 * q + 1] = a.y; w[4 * q + 2] = a.z; w[4 * q + 3] = a.w;
    }
    float bj = b[j];
    for (int t = slot; t < TT; t += 4) {
        const float4* xr = (const float4*)(X + ((size_t)n * TT + t) * HH);
        const float4* ar = (const float4*)(XA + ((size_t)n * TT + t) * HH);
        float acc = bj;
#pragma unroll
        for (int q = 0; q < 16; ++q) {
            float4 v = xr[q];   // wave-uniform -> scalar loads
            acc += v.x * w[4 * q + 0] + v.y * w[4 * q + 1]
                 + v.z * w[4 * q + 2] + v.w * w[4 * q + 3];
        }
#pragma unroll
        for (int q = 0; q < 16; ++q) {
            float4 v = ar[q];
            acc += v.x * w[64 + 4 * q + 0] + v.y * w[64 + 4 * q + 1]
                 + v.z * w[64 + 4 * q + 2] + v.w * w[64 + 4 * q + 3];
        }
        OUT[((size_t)n * TT + t) * HH + j] = fmaxf(acc, 0.f);
    }
}

// ---------------- GCN xw: row @ W^T (no bias), register-weight ----------------
__global__ __launch_bounds__(256) void k_xw(const float* __restrict__ IN,
                                            const float* __restrict__ W,
                                            float* __restrict__ OUT) {
    int tid = threadIdx.x;
    int slot = tid >> 6, j = tid & 63;
    int n = blockIdx.x;
    float w[HH];
    const float4* w4 = (const float4*)(W + (size_t)j * HH);
#pragma unroll
    for (int q = 0; q < 16; ++q) {
        float4 a = w4[q];
        w[4 * q + 0] = a.x; w[4 * q + 1] = a.y; w[4 * q + 2] = a.z; w[4 * q + 3] = a.w;
    }
    for (int t = slot; t < TT; t += 4) {
        const float4* xr = (const float4*)(IN + ((size_t)n * TT + t) * HH);
        float acc = 0.f;
#pragma unroll
        for (int q = 0; q < 16; ++q) {
            float4 v = xr[q];   // wave-uniform -> scalar loads
            acc += v.x * w[4 * q + 0] + v.y * w[4 * q + 1]
                 + v.z * w[4 * q + 2] + v.w * w[4 * q + 3];
        }
        OUT[((size_t)n * TT + t) * HH + j] = acc;
    }
}

// ---------------- GCN aggregate (CSR) + bias + BN + relu, column-chunked ----------------
__global__ __launch_bounds__(256) void k_agg(const float* __restrict__ XW,
                                             const int* __restrict__ off,
                                             const int* __restrict__ csr_src,
                                             const float* __restrict__ csr_nrm,
                                             const float* __restrict__ bias,
                                             const float* __restrict__ g,
                                             const float* __restrict__ bb,
                                             const float* __restrict__ m,
                                             const float* __restrict__ v,
                                             float* __restrict__ OUT) {
    int dst = blockIdx.x, ch = blockIdx.y, tid = threadIdx.x;
    int base = ch * 1024 + tid * 4;
    float4 acc = make_float4(0.f, 0.f, 0.f, 0.f);
    int beg = off[dst], end = off[dst + 1];
    for (int e = beg; e < end; ++e) {
        int src = csr_src[e];
        float w = csr_nrm[e];
        float4 x = *(const float4*)(XW + (size_t)src * THL + base);
        acc.x += w * x.x; acc.y += w * x.y; acc.z += w * x.z; acc.w += w * x.w;
    }
    int h0 = base & 63;   // tid*4 aligned, no wrap within float4
    float4 bs = *(const float4*)(bias + h0);
    float4 gv = *(const float4*)(g + h0);
    float4 vv = *(const float4*)(v + h0);
    float4 mv = *(const float4*)(m + h0);
    float4 bv = *(const float4*)(bb + h0);
    float4 o;
    o.x = fmaxf((acc.x + bs.x - mv.x) * rsqrtf(vv.x + EPSBN) * gv.x + bv.x, 0.f);
    o.y = fmaxf((acc.y + bs.y - mv.y) * rsqrtf(vv.y + EPSBN) * gv.y + bv.y, 0.f);
    o.z = fmaxf((acc.z + bs.z - mv.z) * rsqrtf(vv.z + EPSBN) * gv.z + bv.z, 0.f);
    o.w = fmaxf((acc.w + bs.w - mv.w) * rsqrtf(vv.w + EPSBN) * gv.w + bv.w, 0.f);
    *(float4*)(OUT + (size_t)dst * THL + base) = o;
}

// ---------------- GRU part A: gi = X @ wih^T + bih for a 16-step chunk ----------------
__global__ __launch_bounds__(192) void k_gi(const float* __restrict__ IN,
                                            const float* __restrict__ wih,
                                            const float* __restrict__ bih,
                                            float* __restrict__ GI, int t0) {
    int j = threadIdx.x;
    int n = blockIdx.x;
    float w[64];
    const float4* w4 = (const float4*)(wih + (size_t)j * HH);
#pragma unroll
    for (int q = 0; q < 16; ++q) {
        float4 a = w4[q];
        w[4 * q + 0] = a.x; w[4 * q + 1] = a.y; w[4 * q + 2] = a.z; w[4 * q + 3] = a.w;
    }
    float bias = bih[j];
    float* gout = GI + (size_t)n * (CHT * 192);
    for (int tc = 0; tc < CHT; ++tc) {
        const float4* xr = (const float4*)(IN + ((size_t)n * TT + t0 + tc) * HH);
        float acc = bias;
#pragma unroll
        for (int q = 0; q < 16; ++q) {
            float4 v = xr[q];
            acc += v.x * w[4 * q + 0] + v.y * w[4 * q + 1]
                 + v.z * w[4 * q + 2] + v.w * w[4 * q + 3];
        }
        gout[tc * 192 + j] = acc;
    }
}

// ---------------- GRU part B: recurrence, one wave per node ----------------
__global__ __launch_bounds__(256, 2) void k_rec(const float* __restrict__ GI,
                                                const float* __restrict__ whh,
                                                const float* __restrict__ bhh,
                                                float* __restrict__ hstate,
                                                float* __restrict__ yout,
                                                int t0, int first) {
    int tid = threadIdx.x;
    int wv = tid >> 6, j = tid & 63;
    int n = blockIdx.x * 4 + wv;
    float wr[64], wz[64], wn[64];
    const float4* w4 = (const float4*)whh;
#pragma unroll
    for (int q = 0; q < 16; ++q) {
        float4 a = w4[(size_t)j * 16 + q];
        float4 b = w4[(size_t)(64 + j) * 16 + q];
        float4 c = w4[(size_t)(128 + j) * 16 + q];
        wr[4 * q + 0] = a.x; wr[4 * q + 1] = a.y; wr[4 * q + 2] = a.z; wr[4 * q + 3] = a.w;
        wz[4 * q + 0] = b.x; wz[4 * q + 1] = b.y; wz[4 * q + 2] = b.z; wz[4 * q + 3] = b.w;
        wn[4 * q + 0] = c.x; wn[4 * q + 1] = c.y; wn[4 * q + 2] = c.z; wn[4 * q + 3] = c.w;
    }
    float bhr = bhh[j], bhz = bhh[64 + j], bhn = bhh[128 + j];
    float h = first ? 0.f : hstate[(size_t)n * HH + j];
    const float* gp = GI + (size_t)n * (CHT * 192);
    for (int tc = 0; tc < CHT; ++tc) {
        float gr = gp[tc * 192 + j];
        float gz = gp[tc * 192 + 64 + j];
        float gn = gp[tc * 192 + 128 + j];
        float ar = bhr, az = bhz, an = bhn;
#pragma unroll
        for (int k = 0; k < 64; ++k) {
            float s = __int_as_float(__builtin_amdgcn_readlane(__float_as_int(h), k));
            ar += s * wr[k]; az += s * wz[k]; an += s * wn[k];
        }
        float r = fsigmoid(gr + ar);
        float z = fsigmoid(gz + az);
        float nn2 = tanhf(gn + r * an);
        h = (1.f - z) * nn2 + z * h;
        if (yout) yout[((size_t)n * TT + (t0 + tc)) * HH + j] = h;
    }
    hstate[(size_t)n * HH + j] = h;
}

// ---------------- head: BN + relu + linear + log_softmax ----------------
__global__ __launch_bounds__(256) void k_head(const float* __restrict__ Hf,
                                              const float* __restrict__ g, const float* __restrict__ b,
                                              const float* __restrict__ m, const float* __restrict__ v,
                                              const float* __restrict__ W, const float* __restrict__ wb,
                                              float* __restrict__ out) {
    __shared__ float hb[4][HH];
    __shared__ float lg[4][CC];
    int tid = threadIdx.x;
    int n0 = blockIdx.x * 4;
    int wv = tid >> 6, lane = tid & 63;
    int n = n0 + wv;
    float x = Hf[(size_t)n * HH + lane];
    x = (x - m[lane]) * rsqrtf(v[lane] + EPSBN) * g[lane] + b[lane];
    hb[wv][lane] = fmaxf(x, 0.f);
    __syncthreads();
    if (tid < 4 * CC) {
        int nn = tid / CC, c = tid % CC;
        float acc = wb[c];
        for (int f = 0; f < HH; ++f) acc += hb[nn][f] * W[c * HH + f];
        lg[nn][c] = acc;
    }
    __syncthreads();
    if (tid < 4 * CC) {
        int nn = tid / CC, c = tid % CC;
        float mx = -1e30f;
#pragma unroll
        for (int i = 0; i < CC; ++i) mx = fmaxf(mx, lg[nn][i]);
        float s = 0.f;
#pragma unroll
        for (int i = 0; i < CC; ++i) s += __expf(lg[nn][i] - mx);
        out[(size_t)(n0 + nn) * CC + c] = lg[nn][c] - mx - __logf(s);
    }
}

// ---------------- launch ----------------
extern "C" void kernel_launch(void* const* d_in, const int* in_sizes, int n_in,
                              void* d_out, int out_size, void* d_ws, size_t ws_size,
                              hipStream_t stream) {
    const float* x_seq     = (const float*)d_in[0];
    const int*   edge_idx  = (const int*)d_in[1];
    const float* edge_w    = (const float*)d_in[2];
    const float* causal_w  = (const float*)d_in[3];
    const float* lin_in_w  = (const float*)d_in[4];
    const float* lin_in_b  = (const float*)d_in[5];
    const float* fusion_w  = (const float*)d_in[6];
    const float* fusion_b  = (const float*)d_in[7];
    const float* gcn_w0    = (const float*)d_in[8];
    const float* gcn_b0    = (const float*)d_in[9];
    const float* gcn_w1    = (const float*)d_in[10];
    const float* gcn_b1    = (const float*)d_in[11];
    const float* bn0_g = (const float*)d_in[12], *bn0_b = (const float*)d_in[13];
    const float* bn0_m = (const float*)d_in[14], *bn0_v = (const float*)d_in[15];
    const float* bn1_g = (const float*)d_in[16], *bn1_b = (const float*)d_in[17];
    const float* bn1_m = (const float*)d_in[18], *bn1_v = (const float*)d_in[19];
    const float* wih0 = (const float*)d_in[20], *whh0 = (const float*)d_in[21];
    const float* bih0 = (const float*)d_in[22], *bhh0 = (const float*)d_in[23];
    const float* wih1 = (const float*)d_in[24], *whh1 = (const float*)d_in[25];
    const float* bih1 = (const float*)d_in[26], *bhh1 = (const float*)d_in[27];
    const float* bno_g = (const float*)d_in[28], *bno_b = (const float*)d_in[29];
    const float* bno_m = (const float*)d_in[30], *bno_v = (const float*)d_in[31];
    const float* lout_w = (const float*)d_in[32], *lout_b = (const float*)d_in[33];
    float* out = (float*)d_out;

    float* wsf = (float*)d_ws;
    unsigned short* WCH = (unsigned short*)(wsf + OFF_WC);   // bf16 [2048][2048]
    float* XA  = wsf + OFF_XA;
    float* XB  = wsf + OFF_XB;
    float* XC  = wsf + OFF_XC;
    unsigned short* XAT = (unsigned short*)(wsf + OFF_XC);   // bf16 [4096][2048] (pre-fusion)
    float* DEG = wsf + OFF_DEG;
    int* CNT   = (int*)(wsf + OFF_CNT);
    int* CUR   = (int*)(wsf + OFF_CUR);
    int* OFFP  = (int*)(wsf + OFF_OFF);
    int* CSRS  = (int*)(wsf + OFF_CSRS);
    float* CSRN = wsf + OFF_CSRN;
    float* HST  = wsf + OFF_HST;
    float* GIb  = XB;   // GI chunk buffer reuses XB region during the GRU phase

    // CSR + degree build
    k_zero<<<8, 256, 0, stream>>>(CNT, CUR, DEG);
    k_count<<<(ETOT + 255) / 256, 256, 0, stream>>>(edge_idx, edge_w, CNT, DEG);
    k_scan<<<1, 1024, 0, stream>>>(CNT, OFFP);
    k_fill<<<(ETOT + 255) / 256, 256, 0, stream>>>(edge_idx, edge_w, DEG, OFFP, CUR, CSRS, CSRN);

    // zero WCh (pad rows deterministic)
    hipMemsetAsync(WCH, 0, (size_t)2048 * 2048 * 2, stream);
    // causal softmax -> bf16 WCh
    k_softmax<<<NN, 256, 0, stream>>>(causal_w, WCH);
    // lin_in -> XA [N,T,H] fp32
    k_lin_in<<<NN, 256, 0, stream>>>(x_seq, lin_in_w, lin_in_b, XA);
    // transpose+cast: XA -> XAh_t bf16 [4096][2048]
    dim3 tg(THL / 64, 2048 / 64);
    k_tr<<<tg, 256, 0, stream>>>(XA, XAT);
    // x_agg = WCh @ X (MFMA bf16) -> XB fp32
    dim3 gg(THL / 128, 2048 / 128);
    k_gemm_bf<<<gg, 256, 0, stream>>>(WCH, XAT, XB);
    // fusion -> XC (overwrites XAT region; gemm already consumed it)
    k_fusion<<<NN, 256, 0, stream>>>(XA, XB, fusion_w, fusion_b, XC);
    // GCN layer 0: XC -> XB (xw) -> XA (agg+bn+relu)
    k_xw<<<NN, 256, 0, stream>>>(XC, gcn_w0, XB);
    dim3 ag(NN, 4);
    k_agg<<<ag, 256, 0, stream>>>(XB, OFFP, CSRS, CSRN, gcn_b0, bn0_g, bn0_b, bn0_m, bn0_v, XA);
    // GCN layer 1: XA -> XB -> XC
    k_xw<<<NN, 256, 0, stream>>>(XA, gcn_w1, XB);
    k_agg<<<ag, 256, 0, stream>>>(XB, OFFP, CSRS, CSRN, gcn_b1, bn1_g, bn1_b, bn1_m, bn1_v, XC);

    // GRU layer 0: input XC -> all-t output H0 in XA (chunked over T)
    for (int c = 0; c < TT / CHT; ++c) {
        k_gi<<<NN, 192, 0, stream>>>(XC, wih0, bih0, GIb, c * CHT);
        k_rec<<<NN / 4, 256, 0, stream>>>(GIb, whh0, bhh0, HST, XA, c * CHT, c == 0);
    }
    // GRU layer 1: input XA (H0) -> final h in HST
    for (int c = 0; c < TT / CHT; ++c) {
        k_gi<<<NN, 192, 0, stream>>>(XA, wih1, bih1, GIb, c * CHT);
        k_rec<<<NN / 4, 256, 0, stream>>>(GIb, whh1, bhh1, HST, (float*)nullptr, c * CHT, c == 0);
    }
    // head
    k_head<<<NN / 4, 256, 0, stream>>>(HST, bno_g, bno_b, bno_m, bno_v, lout_w, lout_b, out);
}

// Round 5
// 1164.696 us; speedup vs baseline: 1.6737x; 1.0931x over previous
//
#include <hip/hip_runtime.h>
#include <hip/hip_bf16.h>
#include <math.h>

#define TT 64
#define NN 2000
#define FIN 32
#define HH 64
#define CC 10
#define EE 32000
#define ETOT 34000   // E + N self loops
#define THL 4096     // T*H
#define EPSBN 1e-5f
#define CHT 16       // GRU time-chunk

// ---------------- workspace layout (float offsets) ----------------
#define OFF_WC   0u          // WCh bf16 [2048][2048] = 8.39 MB (region 16 MB)
#define OFF_XA   4000000u    // 8,192,000  [N,T,H] fp32
#define OFF_XB   12192000u   // 8,192,000  (x_agg fp32; also GI chunk buffer)
#define OFF_XC   20384000u   // 8,192,000  (first: XAh_t bf16 [4096][2048]; then fusion out fp32)
#define OFF_DEG  28576000u   // 2048
#define OFF_H1   28578048u   // 128,000 (unused)
#define OFF_CNT  28706048u   // int 2048
#define OFF_CUR  28708096u   // int 2048
#define OFF_OFF  28710144u   // int 2064
#define OFF_CSRS 28712208u   // int 34016
#define OFF_CSRN 28746224u   // float 34016
#define OFF_HST  28780240u   // float 128,000  (GRU h-state)
// total ≈ 28,908,240 floats ≈ 115.6 MB

typedef __attribute__((ext_vector_type(8))) short short8v;
typedef __attribute__((ext_vector_type(4))) float f32x4;

__device__ __forceinline__ float fsigmoid(float x) { return 1.f / (1.f + __expf(-x)); }
__device__ __forceinline__ unsigned short f2bf(float f) {
    __hip_bfloat16 h = __float2bfloat16(f);
    return *reinterpret_cast<unsigned short*>(&h);
}
__device__ __forceinline__ float dot4(float4 v, const float* w) {
    return v.x * w[0] + v.y * w[1] + v.z * w[2] + v.w * w[3];
}

// ---------------- CSR build ----------------
__global__ void k_zero(int* cnt, int* cur, float* deg) {
    int i = blockIdx.x * 256 + threadIdx.x;
    if (i < 2048) { cnt[i] = 0; cur[i] = 0; deg[i] = 0.f; }
}

__global__ void k_count(const int* __restrict__ ei, const float* __restrict__ ew,
                        int* cnt, float* deg) {
    int e = blockIdx.x * 256 + threadIdx.x;
    if (e < ETOT) {
        int dst; float w;
        if (e < EE) { dst = ei[EE + e]; w = ew[e]; }
        else        { dst = e - EE;     w = 1.f; }
        atomicAdd(&cnt[dst], 1);
        atomicAdd(&deg[dst], w);
    }
}

__global__ __launch_bounds__(1024) void k_scan(const int* __restrict__ cnt, int* off) {
    __shared__ int s[2048];
    int tid = threadIdx.x;
    s[tid]        = (tid        < NN) ? cnt[tid]        : 0;
    s[tid + 1024] = (tid + 1024 < NN) ? cnt[tid + 1024] : 0;
    __syncthreads();
    for (int d = 1; d < 2048; d <<= 1) {
        int idx = (tid + 1) * (d << 1) - 1;
        if (idx < 2048) s[idx] += s[idx - d];
        __syncthreads();
    }
    if (tid == 0) s[2047] = 0;
    __syncthreads();
    for (int d = 1024; d >= 1; d >>= 1) {
        int idx = (tid + 1) * (d << 1) - 1;
        if (idx < 2048) { int t = s[idx - d]; s[idx - d] = s[idx]; s[idx] += t; }
        __syncthreads();
    }
    off[tid] = s[tid];
    off[tid + 1024] = s[tid + 1024];
}

__global__ void k_fill(const int* __restrict__ ei, const float* __restrict__ ew,
                       const float* __restrict__ deg, const int* __restrict__ off,
                       int* cur, int* csr_src, float* csr_nrm) {
    int e = blockIdx.x * 256 + threadIdx.x;
    if (e < ETOT) {
        int src, dst; float w;
        if (e < EE) { src = ei[e]; dst = ei[EE + e]; w = ew[e]; }
        else        { src = dst = e - EE;            w = 1.f; }
        float ds = rsqrtf(fmaxf(deg[src], 1e-12f));
        float dd = rsqrtf(fmaxf(deg[dst], 1e-12f));
        int pos = off[dst] + atomicAdd(&cur[dst], 1);
        csr_src[pos] = src;
        csr_nrm[pos] = ds * w * dd;
    }
}

// ---------------- softmax over causal_weight rows -> bf16 WCh [2048 stride] ----------------
__global__ __launch_bounds__(256) void k_softmax(const float* __restrict__ CW,
                                                 unsigned short* __restrict__ WCH) {
    __shared__ float row[NN];
    __shared__ float red[256];
    int r = blockIdx.x, tid = threadIdx.x;
    const float* in = CW + (size_t)r * NN;
    float mx = -1e30f;
    for (int i = tid; i < NN; i += 256) { float v = in[i]; row[i] = v; mx = fmaxf(mx, v); }
    red[tid] = mx; __syncthreads();
    for (int s = 128; s > 0; s >>= 1) {
        if (tid < s) red[tid] = fmaxf(red[tid], red[tid + s]);
        __syncthreads();
    }
    mx = red[0]; __syncthreads();
    float sm = 0.f;
    for (int i = tid; i < NN; i += 256) { float e = __expf(row[i] - mx); row[i] = e; sm += e; }
    red[tid] = sm; __syncthreads();
    for (int s = 128; s > 0; s >>= 1) {
        if (tid < s) red[tid] += red[tid + s];
        __syncthreads();
    }
    float inv = 1.f / red[0];
    unsigned short* out = WCH + (size_t)r * 2048;
    for (int i = tid; i < 2048; i += 256)
        out[i] = (i < NN) ? f2bf(row[i] * inv) : (unsigned short)0;
}

// ---------------- lin_in: relu(x_seq @ W^T + b) -> [N,T,H] fp32, 4-way t-ILP ----------------
__global__ __launch_bounds__(256) void k_lin_in(const float* __restrict__ XS,
                                                const float* __restrict__ W,
                                                const float* __restrict__ b,
                                                float* __restrict__ OUT) {
    int tid = threadIdx.x;
    int slot = tid >> 6, j = tid & 63;
    int n = blockIdx.x;
    float w[FIN];
    const float4* w4 = (const float4*)(W + (size_t)j * FIN);
#pragma unroll
    for (int q = 0; q < 8; ++q) {
        float4 a = w4[q];
        w[4 * q + 0] = a.x; w[4 * q + 1] = a.y; w[4 * q + 2] = a.z; w[4 * q + 3] = a.w;
    }
    float bj = b[j];
    float* obase = OUT + (size_t)n * TT * HH;
#pragma unroll 1
    for (int g = 0; g < 4; ++g) {
        int t0 = slot * 16 + g * 4;
        const float4* x0 = (const float4*)(XS + ((size_t)(t0 + 0) * NN + n) * FIN);
        const float4* x1 = (const float4*)(XS + ((size_t)(t0 + 1) * NN + n) * FIN);
        const float4* x2 = (const float4*)(XS + ((size_t)(t0 + 2) * NN + n) * FIN);
        const float4* x3 = (const float4*)(XS + ((size_t)(t0 + 3) * NN + n) * FIN);
        float a0 = bj, a1 = bj, a2 = bj, a3 = bj;
#pragma unroll
        for (int q = 0; q < 8; ++q) {
            a0 += dot4(x0[q], &w[4 * q]);
            a1 += dot4(x1[q], &w[4 * q]);
            a2 += dot4(x2[q], &w[4 * q]);
            a3 += dot4(x3[q], &w[4 * q]);
        }
        obase[(size_t)(t0 + 0) * HH + j] = fmaxf(a0, 0.f);
        obase[(size_t)(t0 + 1) * HH + j] = fmaxf(a1, 0.f);
        obase[(size_t)(t0 + 2) * HH + j] = fmaxf(a2, 0.f);
        obase[(size_t)(t0 + 3) * HH + j] = fmaxf(a3, 0.f);
    }
}

// ---------------- transpose + bf16 cast: XA [2048(k),4096(c)] -> XAh_t [4096(c),2048(k)] ----------------
__global__ __launch_bounds__(256) void k_tr(const float* __restrict__ X,
                                            unsigned short* __restrict__ XT) {
    __shared__ unsigned short tile[64][65];
    int cb = blockIdx.x * 64;   // c dim
    int kb = blockIdx.y * 64;   // k dim
    int tid = threadIdx.x;
    int r = tid >> 2, cq = tid & 3;
    const float4* src = (const float4*)(X + (size_t)(kb + r) * THL + cb + cq * 16);
#pragma unroll
    for (int j = 0; j < 4; ++j) {
        float4 v = src[j];
        tile[cq * 16 + j * 4 + 0][r] = f2bf(v.x);
        tile[cq * 16 + j * 4 + 1][r] = f2bf(v.y);
        tile[cq * 16 + j * 4 + 2][r] = f2bf(v.z);
        tile[cq * 16 + j * 4 + 3][r] = f2bf(v.w);
    }
    __syncthreads();
    int cl = tid >> 2, kq = tid & 3;
    unsigned short tmp[16];
#pragma unroll
    for (int j = 0; j < 16; ++j) tmp[j] = tile[cl][kq * 16 + j];
    unsigned short* dst = XT + (size_t)(cb + cl) * 2048 + kb + kq * 16;
    *(uint4*)dst = *(uint4*)tmp;
    *(uint4*)(dst + 8) = *(uint4*)(tmp + 8);
}

// ---------------- bf16 MFMA GEMM: C[2000,4096] = WCh[2048,2048] @ X (via XAh_t[4096,2048]) ----------------
__global__ __launch_bounds__(256) void k_gemm_bf(const unsigned short* __restrict__ A,
                                                 const unsigned short* __restrict__ B,
                                                 float* __restrict__ C) {
    __shared__ unsigned short As[128][72];   // stride 144B -> 2-way bank alias (free)
    __shared__ unsigned short Bs[128][72];
    int tid = threadIdx.x;
    int mb = blockIdx.y * 128, nb = blockIdx.x * 128;
    int w = tid >> 6, lane = tid & 63;
    int wr = w >> 1, wc = w & 1;
    int l15 = lane & 15, l4 = lane >> 4;
    f32x4 acc[4][4] = {};
    int r = tid >> 1, hf = tid & 1;
    const uint4* ga = (const uint4*)(A + (size_t)(mb + r) * 2048 + hf * 32);
    const uint4* gb = (const uint4*)(B + (size_t)(nb + r) * 2048 + hf * 32);
    for (int kt = 0; kt < 32; ++kt) {
        uint4 va[4], vb[4];
#pragma unroll
        for (int j = 0; j < 4; ++j) { va[j] = ga[j]; vb[j] = gb[j]; }
        ga += 8; gb += 8;   // advance K by 64 bf16
        __syncthreads();    // previous iteration's frag reads done
#pragma unroll
        for (int j = 0; j < 4; ++j) {
            *(uint4*)&As[r][hf * 32 + j * 8] = va[j];
            *(uint4*)&Bs[r][hf * 32 + j * 8] = vb[j];
        }
        __syncthreads();
#pragma unroll
        for (int kk = 0; kk < 2; ++kk) {
            short8v af[4], bfr[4];
#pragma unroll
            for (int f = 0; f < 4; ++f) {
                af[f]  = *(const short8v*)&As[wr * 64 + f * 16 + l15][kk * 32 + l4 * 8];
                bfr[f] = *(const short8v*)&Bs[wc * 64 + f * 16 + l15][kk * 32 + l4 * 8];
            }
#pragma unroll
            for (int fm = 0; fm < 4; ++fm)
#pragma unroll
                for (int fn = 0; fn < 4; ++fn)
                    acc[fm][fn] = __builtin_amdgcn_mfma_f32_16x16x32_bf16(af[fm], bfr[fn], acc[fm][fn], 0, 0, 0);
        }
    }
#pragma unroll
    for (int fm = 0; fm < 4; ++fm) {
        int gr0 = mb + wr * 64 + fm * 16 + l4 * 4;
#pragma unroll
        for (int rr = 0; rr < 4; ++rr) {
            int grow = gr0 + rr;
            if (grow < NN) {
#pragma unroll
                for (int fn = 0; fn < 4; ++fn) {
                    int gcol = nb + wc * 64 + fn * 16 + l15;
                    C[(size_t)grow * THL + gcol] = acc[fm][fn][rr];
                }
            }
        }
    }
}

// ---------------- fusion: relu([x | x_agg] @ W^T + b), register-weight + 4-way t-ILP ----------------
__global__ __launch_bounds__(256) void k_fusion(const float* __restrict__ X,
                                                const float* __restrict__ XA,
                                                const float* __restrict__ W,
                                                const float* __restrict__ b,
                                                float* __restrict__ OUT) {
    int tid = threadIdx.x;
    int slot = tid >> 6, j = tid & 63;
    int n = blockIdx.x;
    float w[2 * HH];
    const float4* w4 = (const float4*)(W + (size_t)j * (2 * HH));
#pragma unroll
    for (int q = 0; q < 32; ++q) {
        float4 a = w4[q];
        w[4 * q + 0] = a.x; w[4 * q + 1] = a.y; w[4 * q + 2] = a.z; w[4 * q + 3] = a.w;
    }
    float bj = b[j];
    const float* xbase = X + (size_t)n * TT * HH;
    const float* abase = XA + (size_t)n * TT * HH;
    float* obase = OUT + (size_t)n * TT * HH;
#pragma unroll 1
    for (int g = 0; g < 4; ++g) {
        int t0 = slot * 16 + g * 4;
        const float4* x0 = (const float4*)(xbase + (size_t)(t0 + 0) * HH);
        const float4* x1 = (const float4*)(xbase + (size_t)(t0 + 1) * HH);
        const float4* x2 = (const float4*)(xbase + (size_t)(t0 + 2) * HH);
        const float4* x3 = (const float4*)(xbase + (size_t)(t0 + 3) * HH);
        float a0 = bj, a1 = bj, a2 = bj, a3 = bj;
#pragma unroll
        for (int q = 0; q < 16; ++q) {
            a0 += dot4(x0[q], &w[4 * q]);
            a1 += dot4(x1[q], &w[4 * q]);
            a2 += dot4(x2[q], &w[4 * q]);
            a3 += dot4(x3[q], &w[4 * q]);
        }
        const float4* y0 = (const float4*)(abase + (size_t)(t0 + 0) * HH);
        const float4* y1 = (const float4*)(abase + (size_t)(t0 + 1) * HH);
        const float4* y2 = (const float4*)(abase + (size_t)(t0 + 2) * HH);
        const float4* y3 = (const float4*)(abase + (size_t)(t0 + 3) * HH);
#pragma unroll
        for (int q = 0; q < 16; ++q) {
            a0 += dot4(y0[q], &w[64 + 4 * q]);
            a1 += dot4(y1[q], &w[64 + 4 * q]);
            a2 += dot4(y2[q], &w[64 + 4 * q]);
            a3 += dot4(y3[q], &w[64 + 4 * q]);
        }
        obase[(size_t)(t0 + 0) * HH + j] = fmaxf(a0, 0.f);
        obase[(size_t)(t0 + 1) * HH + j] = fmaxf(a1, 0.f);
        obase[(size_t)(t0 + 2) * HH + j] = fmaxf(a2, 0.f);
        obase[(size_t)(t0 + 3) * HH + j] = fmaxf(a3, 0.f);
    }
}

// ---------------- GCN xw: row @ W^T (no bias), register-weight + 4-way t-ILP ----------------
__global__ __launch_bounds__(256) void k_xw(const float* __restrict__ IN,
                                            const float* __restrict__ W,
                                            float* __restrict__ OUT) {
    int tid = threadIdx.x;
    int slot = tid >> 6, j = tid & 63;
    int n = blockIdx.x;
    float w[HH];
    const float4* w4 = (const float4*)(W + (size_t)j * HH);
#pragma unroll
    for (int q = 0; q < 16; ++q) {
        float4 a = w4[q];
        w[4 * q + 0] = a.x; w[4 * q + 1] = a.y; w[4 * q + 2] = a.z; w[4 * q + 3] = a.w;
    }
    const float* xbase = IN + (size_t)n * TT * HH;
    float* obase = OUT + (size_t)n * TT * HH;
#pragma unroll 1
    for (int g = 0; g < 4; ++g) {
        int t0 = slot * 16 + g * 4;
        const float4* x0 = (const float4*)(xbase + (size_t)(t0 + 0) * HH);
        const float4* x1 = (const float4*)(xbase + (size_t)(t0 + 1) * HH);
        const float4* x2 = (const float4*)(xbase + (size_t)(t0 + 2) * HH);
        const float4* x3 = (const float4*)(xbase + (size_t)(t0 + 3) * HH);
        float a0 = 0.f, a1 = 0.f, a2 = 0.f, a3 = 0.f;
#pragma unroll
        for (int q = 0; q < 16; ++q) {
            a0 += dot4(x0[q], &w[4 * q]);
            a1 += dot4(x1[q], &w[4 * q]);
            a2 += dot4(x2[q], &w[4 * q]);
            a3 += dot4(x3[q], &w[4 * q]);
        }
        obase[(size_t)(t0 + 0) * HH + j] = a0;
        obase[(size_t)(t0 + 1) * HH + j] = a1;
        obase[(size_t)(t0 + 2) * HH + j] = a2;
        obase[(size_t)(t0 + 3) * HH + j] = a3;
    }
}

// ---------------- GCN aggregate (CSR) + bias + BN + relu, column-chunked ----------------
__global__ __launch_bounds__(256) void k_agg(const float* __restrict__ XW,
                                             const int* __restrict__ off,
                                             const int* __restrict__ csr_src,
                                             const float* __restrict__ csr_nrm,
                                             const float* __restrict__ bias,
                                             const float* __restrict__ g,
                                             const float* __restrict__ bb,
                                             const float* __restrict__ m,
                                             const float* __restrict__ v,
                                             float* __restrict__ OUT) {
    int dst = blockIdx.x, ch = blockIdx.y, tid = threadIdx.x;
    int base = ch * 1024 + tid * 4;
    float4 acc = make_float4(0.f, 0.f, 0.f, 0.f);
    int beg = off[dst], end = off[dst + 1];
    for (int e = beg; e < end; ++e) {
        int src = csr_src[e];
        float w = csr_nrm[e];
        float4 x = *(const float4*)(XW + (size_t)src * THL + base);
        acc.x += w * x.x; acc.y += w * x.y; acc.z += w * x.z; acc.w += w * x.w;
    }
    int h0 = base & 63;   // tid*4 aligned, no wrap within float4
    float4 bs = *(const float4*)(bias + h0);
    float4 gv = *(const float4*)(g + h0);
    float4 vv = *(const float4*)(v + h0);
    float4 mv = *(const float4*)(m + h0);
    float4 bv = *(const float4*)(bb + h0);
    float4 o;
    o.x = fmaxf((acc.x + bs.x - mv.x) * rsqrtf(vv.x + EPSBN) * gv.x + bv.x, 0.f);
    o.y = fmaxf((acc.y + bs.y - mv.y) * rsqrtf(vv.y + EPSBN) * gv.y + bv.y, 0.f);
    o.z = fmaxf((acc.z + bs.z - mv.z) * rsqrtf(vv.z + EPSBN) * gv.z + bv.z, 0.f);
    o.w = fmaxf((acc.w + bs.w - mv.w) * rsqrtf(vv.w + EPSBN) * gv.w + bv.w, 0.f);
    *(float4*)(OUT + (size_t)dst * THL + base) = o;
}

// ---------------- GRU part A: gi = X @ wih^T + bih, 16-step chunk, 4-way t-ILP ----------------
__global__ __launch_bounds__(192) void k_gi(const float* __restrict__ IN,
                                            const float* __restrict__ wih,
                                            const float* __restrict__ bih,
                                            float* __restrict__ GI, int t0) {
    int j = threadIdx.x;
    int n = blockIdx.x;
    float w[64];
    const float4* w4 = (const float4*)(wih + (size_t)j * HH);
#pragma unroll
    for (int q = 0; q < 16; ++q) {
        float4 a = w4[q];
        w[4 * q + 0] = a.x; w[4 * q + 1] = a.y; w[4 * q + 2] = a.z; w[4 * q + 3] = a.w;
    }
    float bias = bih[j];
    const float* xbase = IN + ((size_t)n * TT + t0) * HH;
    float* gout = GI + (size_t)n * (CHT * 192);
#pragma unroll 1
    for (int g = 0; g < CHT / 4; ++g) {
        const float4* x0 = (const float4*)(xbase + (size_t)(g * 4 + 0) * HH);
        const float4* x1 = (const float4*)(xbase + (size_t)(g * 4 + 1) * HH);
        const float4* x2 = (const float4*)(xbase + (size_t)(g * 4 + 2) * HH);
        const float4* x3 = (const float4*)(xbase + (size_t)(g * 4 + 3) * HH);
        float a0 = bias, a1 = bias, a2 = bias, a3 = bias;
#pragma unroll
        for (int q = 0; q < 16; ++q) {
            a0 += dot4(x0[q], &w[4 * q]);
            a1 += dot4(x1[q], &w[4 * q]);
            a2 += dot4(x2[q], &w[4 * q]);
            a3 += dot4(x3[q], &w[4 * q]);
        }
        gout[(g * 4 + 0) * 192 + j] = a0;
        gout[(g * 4 + 1) * 192 + j] = a1;
        gout[(g * 4 + 2) * 192 + j] = a2;
        gout[(g * 4 + 3) * 192 + j] = a3;
    }
}

// ---------------- GRU part B: recurrence, one wave per node ----------------
__global__ __launch_bounds__(256, 2) void k_rec(const float* __restrict__ GI,
                                                const float* __restrict__ whh,
                                                const float* __restrict__ bhh,
                                                float* __restrict__ hstate,
                                                float* __restrict__ yout,
                                                int t0, int first) {
    int tid = threadIdx.x;
    int wv = tid >> 6, j = tid & 63;
    int n = blockIdx.x * 4 + wv;
    float wr[64], wz[64], wn[64];
    const float4* w4 = (const float4*)whh;
#pragma unroll
    for (int q = 0; q < 16; ++q) {
        float4 a = w4[(size_t)j * 16 + q];
        float4 b = w4[(size_t)(64 + j) * 16 + q];
        float4 c = w4[(size_t)(128 + j) * 16 + q];
        wr[4 * q + 0] = a.x; wr[4 * q + 1] = a.y; wr[4 * q + 2] = a.z; wr[4 * q + 3] = a.w;
        wz[4 * q + 0] = b.x; wz[4 * q + 1] = b.y; wz[4 * q + 2] = b.z; wz[4 * q + 3] = b.w;
        wn[4 * q + 0] = c.x; wn[4 * q + 1] = c.y; wn[4 * q + 2] = c.z; wn[4 * q + 3] = c.w;
    }
    float bhr = bhh[j], bhz = bhh[64 + j], bhn = bhh[128 + j];
    float h = first ? 0.f : hstate[(size_t)n * HH + j];
    const float* gp = GI + (size_t)n * (CHT * 192);
    for (int tc = 0; tc < CHT; ++tc) {
        float gr = gp[tc * 192 + j];
        float gz = gp[tc * 192 + 64 + j];
        float gn = gp[tc * 192 + 128 + j];
        float ar = bhr, az = bhz, an = bhn;
#pragma unroll
        for (int k = 0; k < 64; ++k) {
            float s = __int_as_float(__builtin_amdgcn_readlane(__float_as_int(h), k));
            ar += s * wr[k]; az += s * wz[k]; an += s * wn[k];
        }
        float r = fsigmoid(gr + ar);
        float z = fsigmoid(gz + az);
        float nn2 = tanhf(gn + r * an);
        h = (1.f - z) * nn2 + z * h;
        if (yout) yout[((size_t)n * TT + (t0 + tc)) * HH + j] = h;
    }
    hstate[(size_t)n * HH + j] = h;
}

// ---------------- head: BN + relu + linear + log_softmax ----------------
__global__ __launch_bounds__(256) void k_head(const float* __restrict__ Hf,
                                              const float* __restrict__ g, const float* __restrict__ b,
                                              const float* __restrict__ m, const float* __restrict__ v,
                                              const float* __restrict__ W, const float* __restrict__ wb,
                                              float* __restrict__ out) {
    __shared__ float hb[4][HH];
    __shared__ float lg[4][CC];
    int tid = threadIdx.x;
    int n0 = blockIdx.x * 4;
    int wv = tid >> 6, lane = tid & 63;
    int n = n0 + wv;
    float x = Hf[(size_t)n * HH + lane];
    x = (x - m[lane]) * rsqrtf(v[lane] + EPSBN) * g[lane] + b[lane];
    hb[wv][lane] = fmaxf(x, 0.f);
    __syncthreads();
    if (tid < 4 * CC) {
        int nn = tid / CC, c = tid % CC;
        float acc = wb[c];
        for (int f = 0; f < HH; ++f) acc += hb[nn][f] * W[c * HH + f];
        lg[nn][c] = acc;
    }
    __syncthreads();
    if (tid < 4 * CC) {
        int nn = tid / CC, c = tid % CC;
        float mx = -1e30f;
#pragma unroll
        for (int i = 0; i < CC; ++i) mx = fmaxf(mx, lg[nn][i]);
        float s = 0.f;
#pragma unroll
        for (int i = 0; i < CC; ++i) s += __expf(lg[nn][i] - mx);
        out[(size_t)(n0 + nn) * CC + c] = lg[nn][c] - mx - __logf(s);
    }
}

// ---------------- launch ----------------
extern "C" void kernel_launch(void* const* d_in, const int* in_sizes, int n_in,
                              void* d_out, int out_size, void* d_ws, size_t ws_size,
                              hipStream_t stream) {
    const float* x_seq     = (const float*)d_in[0];
    const int*   edge_idx  = (const int*)d_in[1];
    const float* edge_w    = (const float*)d_in[2];
    const float* causal_w  = (const float*)d_in[3];
    const float* lin_in_w  = (const float*)d_in[4];
    const float* lin_in_b  = (const float*)d_in[5];
    const float* fusion_w  = (const float*)d_in[6];
    const float* fusion_b  = (const float*)d_in[7];
    const float* gcn_w0    = (const float*)d_in[8];
    const float* gcn_b0    = (const float*)d_in[9];
    const float* gcn_w1    = (const float*)d_in[10];
    const float* gcn_b1    = (const float*)d_in[11];
    const float* bn0_g = (const float*)d_in[12], *bn0_b = (const float*)d_in[13];
    const float* bn0_m = (const float*)d_in[14], *bn0_v = (const float*)d_in[15];
    const float* bn1_g = (const float*)d_in[16], *bn1_b = (const float*)d_in[17];
    const float* bn1_m = (const float*)d_in[18], *bn1_v = (const float*)d_in[19];
    const float* wih0 = (const float*)d_in[20], *whh0 = (const float*)d_in[21];
    const float* bih0 = (const float*)d_in[22], *bhh0 = (const float*)d_in[23];
    const float* wih1 = (const float*)d_in[24], *whh1 = (const float*)d_in[25];
    const float* bih1 = (const float*)d_in[26], *bhh1 = (const float*)d_in[27];
    const float* bno_g = (const float*)d_in[28], *bno_b = (const float*)d_in[29];
    const float* bno_m = (const float*)d_in[30], *bno_v = (const float*)d_in[31];
    const float* lout_w = (const float*)d_in[32], *lout_b = (const float*)d_in[33];
    float* out = (float*)d_out;

    float* wsf = (float*)d_ws;
    unsigned short* WCH = (unsigned short*)(wsf + OFF_WC);   // bf16 [2048][2048]
    float* XA  = wsf + OFF_XA;
    float* XB  = wsf + OFF_XB;
    float* XC  = wsf + OFF_XC;
    unsigned short* XAT = (unsigned short*)(wsf + OFF_XC);   // bf16 [4096][2048] (pre-fusion)
    float* DEG = wsf + OFF_DEG;
    int* CNT   = (int*)(wsf + OFF_CNT);
    int* CUR   = (int*)(wsf + OFF_CUR);
    int* OFFP  = (int*)(wsf + OFF_OFF);
    int* CSRS  = (int*)(wsf + OFF_CSRS);
    float* CSRN = wsf + OFF_CSRN;
    float* HST  = wsf + OFF_HST;
    float* GIb  = XB;   // GI chunk buffer reuses XB region during the GRU phase

    // CSR + degree build
    k_zero<<<8, 256, 0, stream>>>(CNT, CUR, DEG);
    k_count<<<(ETOT + 255) / 256, 256, 0, stream>>>(edge_idx, edge_w, CNT, DEG);
    k_scan<<<1, 1024, 0, stream>>>(CNT, OFFP);
    k_fill<<<(ETOT + 255) / 256, 256, 0, stream>>>(edge_idx, edge_w, DEG, OFFP, CUR, CSRS, CSRN);

    // zero WCh (pad rows deterministic)
    hipMemsetAsync(WCH, 0, (size_t)2048 * 2048 * 2, stream);
    // causal softmax -> bf16 WCh
    k_softmax<<<NN, 256, 0, stream>>>(causal_w, WCH);
    // lin_in -> XA [N,T,H] fp32
    k_lin_in<<<NN, 256, 0, stream>>>(x_seq, lin_in_w, lin_in_b, XA);
    // transpose+cast: XA -> XAh_t bf16 [4096][2048]
    dim3 tg(THL / 64, 2048 / 64);
    k_tr<<<tg, 256, 0, stream>>>(XA, XAT);
    // x_agg = WCh @ X (MFMA bf16) -> XB fp32
    dim3 gg(THL / 128, 2048 / 128);
    k_gemm_bf<<<gg, 256, 0, stream>>>(WCH, XAT, XB);
    // fusion -> XC (overwrites XAT region; gemm already consumed it)
    k_fusion<<<NN, 256, 0, stream>>>(XA, XB, fusion_w, fusion_b, XC);
    // GCN layer 0: XC -> XB (xw) -> XA (agg+bn+relu)
    k_xw<<<NN, 256, 0, stream>>>(XC, gcn_w0, XB);
    dim3 ag(NN, 4);
    k_agg<<<ag, 256, 0, stream>>>(XB, OFFP, CSRS, CSRN, gcn_b0, bn0_g, bn0_b, bn0_m, bn0_v, XA);
    // GCN layer 1: XA -> XB -> XC
    k_xw<<<NN, 256, 0, stream>>>(XA, gcn_w1, XB);
    k_agg<<<ag, 256, 0, stream>>>(XB, OFFP, CSRS, CSRN, gcn_b1, bn1_g, bn1_b, bn1_m, bn1_v, XC);

    // GRU layer 0: input XC -> all-t output H0 in XA (chunked over T)
    for (int c = 0; c < TT / CHT; ++c) {
        k_gi<<<NN, 192, 0, stream>>>(XC, wih0, bih0, GIb, c * CHT);
        k_rec<<<NN / 4, 256, 0, stream>>>(GIb, whh0, bhh0, HST, XA, c * CHT, c == 0);
    }
    // GRU layer 1: input XA (H0) -> final h in HST
    for (int c = 0; c < TT / CHT; ++c) {
        k_gi<<<NN, 192, 0, stream>>>(XA, wih1, bih1, GIb, c * CHT);
        k_rec<<<NN / 4, 256, 0, stream>>>(GIb, whh1, bhh1, HST, (float*)nullptr, c * CHT, c == 0);
    }
    // head
    k_head<<<NN / 4, 256, 0, stream>>>(HST, bno_g, bno_b, bno_m, bno_v, lout_w, lout_b, out);
}

// Round 6
// 791.480 us; speedup vs baseline: 2.4630x; 1.4715x over previous
//
#include <hip/hip_runtime.h>
#include <hip/hip_bf16.h>
#include <math.h>

#define TT 64
#define NN 2000
#define FIN 32
#define HH 64
#define CC 10
#define EE 32000
#define ETOT 34000   // E + N self loops
#define THL 4096     // T*H
#define EPSBN 1e-5f
#define CHT 16       // GRU time-chunk

// ---------------- workspace layout (float offsets) ----------------
#define OFF_WC   0u          // WCh bf16 [2048][2048]
#define OFF_XA   4000000u    // 8,192,000  [N,T,H] fp32
#define OFF_XB   12192000u   // 8,192,000  (x_agg fp32; also GI chunk buffer)
#define OFF_XC   20384000u   // 8,192,000  (first: XAh_t bf16 [4096][2048]; then fusion out fp32)
#define OFF_DEG  28576000u   // 2048
#define OFF_H1   28578048u   // 128,000 (unused)
#define OFF_CNT  28706048u   // int 2048
#define OFF_CUR  28708096u   // int 2048
#define OFF_OFF  28710144u   // int 2064
#define OFF_CSRS 28712208u   // int 34016
#define OFF_CSRN 28746224u   // float 34016
#define OFF_HST  28780240u   // float 128,000  (GRU h-state)

typedef __attribute__((ext_vector_type(8))) short short8v;
typedef __attribute__((ext_vector_type(4))) float f32x4;

__device__ __forceinline__ float fsigmoid(float x) { return 1.f / (1.f + __expf(-x)); }
__device__ __forceinline__ unsigned short f2bf(float f) {
    __hip_bfloat16 h = __float2bfloat16(f);
    return *reinterpret_cast<unsigned short*>(&h);
}

// ---------------- CSR build ----------------
__global__ void k_zero(int* cnt, int* cur, float* deg) {
    int i = blockIdx.x * 256 + threadIdx.x;
    if (i < 2048) { cnt[i] = 0; cur[i] = 0; deg[i] = 0.f; }
}

__global__ void k_count(const int* __restrict__ ei, const float* __restrict__ ew,
                        int* cnt, float* deg) {
    int e = blockIdx.x * 256 + threadIdx.x;
    if (e < ETOT) {
        int dst; float w;
        if (e < EE) { dst = ei[EE + e]; w = ew[e]; }
        else        { dst = e - EE;     w = 1.f; }
        atomicAdd(&cnt[dst], 1);
        atomicAdd(&deg[dst], w);
    }
}

__global__ __launch_bounds__(1024) void k_scan(const int* __restrict__ cnt, int* off) {
    __shared__ int s[2048];
    int tid = threadIdx.x;
    s[tid]        = (tid        < NN) ? cnt[tid]        : 0;
    s[tid + 1024] = (tid + 1024 < NN) ? cnt[tid + 1024] : 0;
    __syncthreads();
    for (int d = 1; d < 2048; d <<= 1) {
        int idx = (tid + 1) * (d << 1) - 1;
        if (idx < 2048) s[idx] += s[idx - d];
        __syncthreads();
    }
    if (tid == 0) s[2047] = 0;
    __syncthreads();
    for (int d = 1024; d >= 1; d >>= 1) {
        int idx = (tid + 1) * (d << 1) - 1;
        if (idx < 2048) { int t = s[idx - d]; s[idx - d] = s[idx]; s[idx] += t; }
        __syncthreads();
    }
    off[tid] = s[tid];
    off[tid + 1024] = s[tid + 1024];
}

__global__ void k_fill(const int* __restrict__ ei, const float* __restrict__ ew,
                       const float* __restrict__ deg, const int* __restrict__ off,
                       int* cur, int* csr_src, float* csr_nrm) {
    int e = blockIdx.x * 256 + threadIdx.x;
    if (e < ETOT) {
        int src, dst; float w;
        if (e < EE) { src = ei[e]; dst = ei[EE + e]; w = ew[e]; }
        else        { src = dst = e - EE;            w = 1.f; }
        float ds = rsqrtf(fmaxf(deg[src], 1e-12f));
        float dd = rsqrtf(fmaxf(deg[dst], 1e-12f));
        int pos = off[dst] + atomicAdd(&cur[dst], 1);
        csr_src[pos] = src;
        csr_nrm[pos] = ds * w * dd;
    }
}

// ---------------- softmax over causal_weight rows -> bf16 WCh [2048 stride] ----------------
__global__ __launch_bounds__(256) void k_softmax(const float* __restrict__ CW,
                                                 unsigned short* __restrict__ WCH) {
    __shared__ float row[NN];
    __shared__ float red[256];
    int r = blockIdx.x, tid = threadIdx.x;
    const float* in = CW + (size_t)r * NN;
    float mx = -1e30f;
    for (int i = tid; i < NN; i += 256) { float v = in[i]; row[i] = v; mx = fmaxf(mx, v); }
    red[tid] = mx; __syncthreads();
    for (int s = 128; s > 0; s >>= 1) {
        if (tid < s) red[tid] = fmaxf(red[tid], red[tid + s]);
        __syncthreads();
    }
    mx = red[0]; __syncthreads();
    float sm = 0.f;
    for (int i = tid; i < NN; i += 256) { float e = __expf(row[i] - mx); row[i] = e; sm += e; }
    red[tid] = sm; __syncthreads();
    for (int s = 128; s > 0; s >>= 1) {
        if (tid < s) red[tid] += red[tid + s];
        __syncthreads();
    }
    float inv = 1.f / red[0];
    unsigned short* out = WCH + (size_t)r * 2048;
    for (int i = tid; i < 2048; i += 256)
        out[i] = (i < NN) ? f2bf(row[i] * inv) : (unsigned short)0;
}

// ---------------- lin_in as tiled GEMM: rows=(n,t), K=32, 64 cols ----------------
__global__ __launch_bounds__(256) void k_lin2(const float* __restrict__ XS,
                                              const float* __restrict__ W,
                                              const float* __restrict__ b,
                                              float* __restrict__ OUT) {
    __shared__ float Wt[FIN][68];   // [k][o]
    __shared__ float As[FIN][68];   // [k][row]
    int tid = threadIdx.x;
    int n = blockIdx.x;
    for (int i = tid; i < HH * FIN; i += 256) { int o = i >> 5, k = i & 31; Wt[k][o] = W[i]; }
    int row = tid >> 2, kq = tid & 3;   // row = t
    {
        const float4* src = (const float4*)(XS + ((size_t)row * NN + n) * FIN + kq * 8);
        float4 v0 = src[0], v1 = src[1];
        As[kq * 8 + 0][row] = v0.x; As[kq * 8 + 1][row] = v0.y;
        As[kq * 8 + 2][row] = v0.z; As[kq * 8 + 3][row] = v0.w;
        As[kq * 8 + 4][row] = v1.x; As[kq * 8 + 5][row] = v1.y;
        As[kq * 8 + 6][row] = v1.z; As[kq * 8 + 7][row] = v1.w;
    }
    __syncthreads();
    int tx = tid & 15, ty = tid >> 4;
    float acc[4][4] = {};
#pragma unroll
    for (int k = 0; k < FIN; ++k) {
        float4 av = *(const float4*)&As[k][ty * 4];
        float4 wv = *(const float4*)&Wt[k][tx * 4];
        acc[0][0] += av.x * wv.x; acc[0][1] += av.x * wv.y; acc[0][2] += av.x * wv.z; acc[0][3] += av.x * wv.w;
        acc[1][0] += av.y * wv.x; acc[1][1] += av.y * wv.y; acc[1][2] += av.y * wv.z; acc[1][3] += av.y * wv.w;
        acc[2][0] += av.z * wv.x; acc[2][1] += av.z * wv.y; acc[2][2] += av.z * wv.z; acc[2][3] += av.z * wv.w;
        acc[3][0] += av.w * wv.x; acc[3][1] += av.w * wv.y; acc[3][2] += av.w * wv.z; acc[3][3] += av.w * wv.w;
    }
    float4 bv = *(const float4*)(b + tx * 4);
#pragma unroll
    for (int ii = 0; ii < 4; ++ii) {
        float4 o;
        o.x = fmaxf(acc[ii][0] + bv.x, 0.f);
        o.y = fmaxf(acc[ii][1] + bv.y, 0.f);
        o.z = fmaxf(acc[ii][2] + bv.z, 0.f);
        o.w = fmaxf(acc[ii][3] + bv.w, 0.f);
        *(float4*)(OUT + ((size_t)n * TT + ty * 4 + ii) * HH + tx * 4) = o;
    }
}

// ---------------- transpose + bf16 cast ----------------
__global__ __launch_bounds__(256) void k_tr(const float* __restrict__ X,
                                            unsigned short* __restrict__ XT) {
    __shared__ unsigned short tile[64][65];
    int cb = blockIdx.x * 64;
    int kb = blockIdx.y * 64;
    int tid = threadIdx.x;
    int r = tid >> 2, cq = tid & 3;
    const float4* src = (const float4*)(X + (size_t)(kb + r) * THL + cb + cq * 16);
#pragma unroll
    for (int j = 0; j < 4; ++j) {
        float4 v = src[j];
        tile[cq * 16 + j * 4 + 0][r] = f2bf(v.x);
        tile[cq * 16 + j * 4 + 1][r] = f2bf(v.y);
        tile[cq * 16 + j * 4 + 2][r] = f2bf(v.z);
        tile[cq * 16 + j * 4 + 3][r] = f2bf(v.w);
    }
    __syncthreads();
    int cl = tid >> 2, kq = tid & 3;
    unsigned short tmp[16];
#pragma unroll
    for (int j = 0; j < 16; ++j) tmp[j] = tile[cl][kq * 16 + j];
    unsigned short* dst = XT + (size_t)(cb + cl) * 2048 + kb + kq * 16;
    *(uint4*)dst = *(uint4*)tmp;
    *(uint4*)(dst + 8) = *(uint4*)(tmp + 8);
}

// ---------------- bf16 MFMA GEMM: C[2000,4096] = WCh @ X (via XAh_t) ----------------
__global__ __launch_bounds__(256) void k_gemm_bf(const unsigned short* __restrict__ A,
                                                 const unsigned short* __restrict__ B,
                                                 float* __restrict__ C) {
    __shared__ unsigned short As[128][72];
    __shared__ unsigned short Bs[128][72];
    int tid = threadIdx.x;
    int mb = blockIdx.y * 128, nb = blockIdx.x * 128;
    int w = tid >> 6, lane = tid & 63;
    int wr = w >> 1, wc = w & 1;
    int l15 = lane & 15, l4 = lane >> 4;
    f32x4 acc[4][4] = {};
    int r = tid >> 1, hf = tid & 1;
    const uint4* ga = (const uint4*)(A + (size_t)(mb + r) * 2048 + hf * 32);
    const uint4* gb = (const uint4*)(B + (size_t)(nb + r) * 2048 + hf * 32);
    for (int kt = 0; kt < 32; ++kt) {
        uint4 va[4], vb[4];
#pragma unroll
        for (int j = 0; j < 4; ++j) { va[j] = ga[j]; vb[j] = gb[j]; }
        ga += 8; gb += 8;
        __syncthreads();
#pragma unroll
        for (int j = 0; j < 4; ++j) {
            *(uint4*)&As[r][hf * 32 + j * 8] = va[j];
            *(uint4*)&Bs[r][hf * 32 + j * 8] = vb[j];
        }
        __syncthreads();
#pragma unroll
        for (int kk = 0; kk < 2; ++kk) {
            short8v af[4], bfr[4];
#pragma unroll
            for (int f = 0; f < 4; ++f) {
                af[f]  = *(const short8v*)&As[wr * 64 + f * 16 + l15][kk * 32 + l4 * 8];
                bfr[f] = *(const short8v*)&Bs[wc * 64 + f * 16 + l15][kk * 32 + l4 * 8];
            }
#pragma unroll
            for (int fm = 0; fm < 4; ++fm)
#pragma unroll
                for (int fn = 0; fn < 4; ++fn)
                    acc[fm][fn] = __builtin_amdgcn_mfma_f32_16x16x32_bf16(af[fm], bfr[fn], acc[fm][fn], 0, 0, 0);
        }
    }
#pragma unroll
    for (int fm = 0; fm < 4; ++fm) {
        int gr0 = mb + wr * 64 + fm * 16 + l4 * 4;
#pragma unroll
        for (int rr = 0; rr < 4; ++rr) {
            int grow = gr0 + rr;
            if (grow < NN) {
#pragma unroll
                for (int fn = 0; fn < 4; ++fn) {
                    int gcol = nb + wc * 64 + fn * 16 + l15;
                    C[(size_t)grow * THL + gcol] = acc[fm][fn][rr];
                }
            }
        }
    }
}

// ---------------- fusion as tiled GEMM: K=128 (two 64-K phases), 64 cols ----------------
__global__ __launch_bounds__(256) void k_fus2(const float* __restrict__ X,
                                              const float* __restrict__ XAgg,
                                              const float* __restrict__ W,
                                              const float* __restrict__ b,
                                              float* __restrict__ OUT) {
    __shared__ float Wt[2 * HH][68];  // [k][o], k = 0..127
    __shared__ float As[HH][68];      // [k][row]
    int tid = threadIdx.x;
    size_t r0 = (size_t)blockIdx.x * 64;
    for (int i = tid; i < HH * 2 * HH; i += 256) { int o = i >> 7, k = i & 127; Wt[k][o] = W[i]; }
    int row = tid >> 2, kq = tid & 3;
    int tx = tid & 15, ty = tid >> 4;
    float acc[4][4] = {};
    const float* srcs[2] = { X, XAgg };
#pragma unroll
    for (int ph = 0; ph < 2; ++ph) {
        __syncthreads();   // protect As from previous phase's readers
        const float4* src = (const float4*)(srcs[ph] + (r0 + row) * HH + kq * 16);
#pragma unroll
        for (int j = 0; j < 4; ++j) {
            float4 v = src[j];
            As[kq * 16 + j * 4 + 0][row] = v.x;
            As[kq * 16 + j * 4 + 1][row] = v.y;
            As[kq * 16 + j * 4 + 2][row] = v.z;
            As[kq * 16 + j * 4 + 3][row] = v.w;
        }
        __syncthreads();
#pragma unroll
        for (int k = 0; k < HH; ++k) {
            float4 av = *(const float4*)&As[k][ty * 4];
            float4 wv = *(const float4*)&Wt[ph * HH + k][tx * 4];
            acc[0][0] += av.x * wv.x; acc[0][1] += av.x * wv.y; acc[0][2] += av.x * wv.z; acc[0][3] += av.x * wv.w;
            acc[1][0] += av.y * wv.x; acc[1][1] += av.y * wv.y; acc[1][2] += av.y * wv.z; acc[1][3] += av.y * wv.w;
            acc[2][0] += av.z * wv.x; acc[2][1] += av.z * wv.y; acc[2][2] += av.z * wv.z; acc[2][3] += av.z * wv.w;
            acc[3][0] += av.w * wv.x; acc[3][1] += av.w * wv.y; acc[3][2] += av.w * wv.z; acc[3][3] += av.w * wv.w;
        }
    }
    float4 bv = *(const float4*)(b + tx * 4);
#pragma unroll
    for (int ii = 0; ii < 4; ++ii) {
        float4 o;
        o.x = fmaxf(acc[ii][0] + bv.x, 0.f);
        o.y = fmaxf(acc[ii][1] + bv.y, 0.f);
        o.z = fmaxf(acc[ii][2] + bv.z, 0.f);
        o.w = fmaxf(acc[ii][3] + bv.w, 0.f);
        *(float4*)(OUT + (r0 + ty * 4 + ii) * HH + tx * 4) = o;
    }
}

// ---------------- GCN xw as tiled GEMM: K=64, 64 cols, no bias ----------------
__global__ __launch_bounds__(256) void k_xw2(const float* __restrict__ IN,
                                             const float* __restrict__ W,
                                             float* __restrict__ OUT) {
    __shared__ float Wt[HH][68];
    __shared__ float As[HH][68];
    int tid = threadIdx.x;
    size_t r0 = (size_t)blockIdx.x * 64;
    for (int i = tid; i < HH * HH; i += 256) { int o = i >> 6, k = i & 63; Wt[k][o] = W[i]; }
    int row = tid >> 2, kq = tid & 3;
    {
        const float4* src = (const float4*)(IN + (r0 + row) * HH + kq * 16);
#pragma unroll
        for (int j = 0; j < 4; ++j) {
            float4 v = src[j];
            As[kq * 16 + j * 4 + 0][row] = v.x;
            As[kq * 16 + j * 4 + 1][row] = v.y;
            As[kq * 16 + j * 4 + 2][row] = v.z;
            As[kq * 16 + j * 4 + 3][row] = v.w;
        }
    }
    __syncthreads();
    int tx = tid & 15, ty = tid >> 4;
    float acc[4][4] = {};
#pragma unroll
    for (int k = 0; k < HH; ++k) {
        float4 av = *(const float4*)&As[k][ty * 4];
        float4 wv = *(const float4*)&Wt[k][tx * 4];
        acc[0][0] += av.x * wv.x; acc[0][1] += av.x * wv.y; acc[0][2] += av.x * wv.z; acc[0][3] += av.x * wv.w;
        acc[1][0] += av.y * wv.x; acc[1][1] += av.y * wv.y; acc[1][2] += av.y * wv.z; acc[1][3] += av.y * wv.w;
        acc[2][0] += av.z * wv.x; acc[2][1] += av.z * wv.y; acc[2][2] += av.z * wv.z; acc[2][3] += av.z * wv.w;
        acc[3][0] += av.w * wv.x; acc[3][1] += av.w * wv.y; acc[3][2] += av.w * wv.z; acc[3][3] += av.w * wv.w;
    }
#pragma unroll
    for (int ii = 0; ii < 4; ++ii) {
        float4 o = make_float4(acc[ii][0], acc[ii][1], acc[ii][2], acc[ii][3]);
        *(float4*)(OUT + (r0 + ty * 4 + ii) * HH + tx * 4) = o;
    }
}

// ---------------- GCN aggregate (CSR) + bias + BN + relu, column-chunked ----------------
__global__ __launch_bounds__(256) void k_agg(const float* __restrict__ XW,
                                             const int* __restrict__ off,
                                             const int* __restrict__ csr_src,
                                             const float* __restrict__ csr_nrm,
                                             const float* __restrict__ bias,
                                             const float* __restrict__ g,
                                             const float* __restrict__ bb,
                                             const float* __restrict__ m,
                                             const float* __restrict__ v,
                                             float* __restrict__ OUT) {
    int dst = blockIdx.x, ch = blockIdx.y, tid = threadIdx.x;
    int base = ch * 1024 + tid * 4;
    float4 acc = make_float4(0.f, 0.f, 0.f, 0.f);
    int beg = off[dst], end = off[dst + 1];
    for (int e = beg; e < end; ++e) {
        int src = csr_src[e];
        float w = csr_nrm[e];
        float4 x = *(const float4*)(XW + (size_t)src * THL + base);
        acc.x += w * x.x; acc.y += w * x.y; acc.z += w * x.z; acc.w += w * x.w;
    }
    int h0 = base & 63;
    float4 bs = *(const float4*)(bias + h0);
    float4 gv = *(const float4*)(g + h0);
    float4 vv = *(const float4*)(v + h0);
    float4 mv = *(const float4*)(m + h0);
    float4 bv = *(const float4*)(bb + h0);
    float4 o;
    o.x = fmaxf((acc.x + bs.x - mv.x) * rsqrtf(vv.x + EPSBN) * gv.x + bv.x, 0.f);
    o.y = fmaxf((acc.y + bs.y - mv.y) * rsqrtf(vv.y + EPSBN) * gv.y + bv.y, 0.f);
    o.z = fmaxf((acc.z + bs.z - mv.z) * rsqrtf(vv.z + EPSBN) * gv.z + bv.z, 0.f);
    o.w = fmaxf((acc.w + bs.w - mv.w) * rsqrtf(vv.w + EPSBN) * gv.w + bv.w, 0.f);
    *(float4*)(OUT + (size_t)dst * THL + base) = o;
}

// ---------------- GRU gi as tiled GEMM: rows=(n,tc) chunk, K=64, 192 cols in 3 slabs ----------------
__global__ __launch_bounds__(256) void k_gi2(const float* __restrict__ IN,
                                             const float* __restrict__ wih,
                                             const float* __restrict__ bih,
                                             float* __restrict__ GI, int t0) {
    __shared__ float Wt[HH][68];
    __shared__ float As[HH][68];
    int tid = threadIdx.x;
    int r0 = blockIdx.x * 64;          // row tile (r = n*CHT + tc)
    int cb = blockIdx.y * 64;          // col slab base (0/64/128)
    for (int i = tid; i < 64 * HH; i += 256) {
        int o = i >> 6, k = i & 63;
        Wt[k][o] = wih[(size_t)(cb + o) * HH + k];
    }
    int row = tid >> 2, kq = tid & 3;
    {
        int rr = r0 + row;
        int n = rr >> 4, tc = rr & 15;
        const float4* src = (const float4*)(IN + ((size_t)n * TT + t0 + tc) * HH + kq * 16);
#pragma unroll
        for (int j = 0; j < 4; ++j) {
            float4 v = src[j];
            As[kq * 16 + j * 4 + 0][row] = v.x;
            As[kq * 16 + j * 4 + 1][row] = v.y;
            As[kq * 16 + j * 4 + 2][row] = v.z;
            As[kq * 16 + j * 4 + 3][row] = v.w;
        }
    }
    __syncthreads();
    int tx = tid & 15, ty = tid >> 4;
    float acc[4][4] = {};
#pragma unroll
    for (int k = 0; k < HH; ++k) {
        float4 av = *(const float4*)&As[k][ty * 4];
        float4 wv = *(const float4*)&Wt[k][tx * 4];
        acc[0][0] += av.x * wv.x; acc[0][1] += av.x * wv.y; acc[0][2] += av.x * wv.z; acc[0][3] += av.x * wv.w;
        acc[1][0] += av.y * wv.x; acc[1][1] += av.y * wv.y; acc[1][2] += av.y * wv.z; acc[1][3] += av.y * wv.w;
        acc[2][0] += av.z * wv.x; acc[2][1] += av.z * wv.y; acc[2][2] += av.z * wv.z; acc[2][3] += av.z * wv.w;
        acc[3][0] += av.w * wv.x; acc[3][1] += av.w * wv.y; acc[3][2] += av.w * wv.z; acc[3][3] += av.w * wv.w;
    }
    float4 bv = *(const float4*)(bih + cb + tx * 4);
#pragma unroll
    for (int ii = 0; ii < 4; ++ii) {
        float4 o;
        o.x = acc[ii][0] + bv.x;
        o.y = acc[ii][1] + bv.y;
        o.z = acc[ii][2] + bv.z;
        o.w = acc[ii][3] + bv.w;
        *(float4*)(GI + (size_t)(r0 + ty * 4 + ii) * 192 + cb + tx * 4) = o;
    }
}

// ---------------- GRU part B: recurrence, one wave per node ----------------
__global__ __launch_bounds__(256, 2) void k_rec(const float* __restrict__ GI,
                                                const float* __restrict__ whh,
                                                const float* __restrict__ bhh,
                                                float* __restrict__ hstate,
                                                float* __restrict__ yout,
                                                int t0, int first) {
    int tid = threadIdx.x;
    int wv = tid >> 6, j = tid & 63;
    int n = blockIdx.x * 4 + wv;
    float wr[64], wz[64], wn[64];
    const float4* w4 = (const float4*)whh;
#pragma unroll
    for (int q = 0; q < 16; ++q) {
        float4 a = w4[(size_t)j * 16 + q];
        float4 b = w4[(size_t)(64 + j) * 16 + q];
        float4 c = w4[(size_t)(128 + j) * 16 + q];
        wr[4 * q + 0] = a.x; wr[4 * q + 1] = a.y; wr[4 * q + 2] = a.z; wr[4 * q + 3] = a.w;
        wz[4 * q + 0] = b.x; wz[4 * q + 1] = b.y; wz[4 * q + 2] = b.z; wz[4 * q + 3] = b.w;
        wn[4 * q + 0] = c.x; wn[4 * q + 1] = c.y; wn[4 * q + 2] = c.z; wn[4 * q + 3] = c.w;
    }
    float bhr = bhh[j], bhz = bhh[64 + j], bhn = bhh[128 + j];
    float h = first ? 0.f : hstate[(size_t)n * HH + j];
    const float* gp = GI + (size_t)n * (CHT * 192);
    for (int tc = 0; tc < CHT; ++tc) {
        float gr = gp[tc * 192 + j];
        float gz = gp[tc * 192 + 64 + j];
        float gn = gp[tc * 192 + 128 + j];
        float ar = bhr, az = bhz, an = bhn;
#pragma unroll
        for (int k = 0; k < 64; ++k) {
            float s = __int_as_float(__builtin_amdgcn_readlane(__float_as_int(h), k));
            ar += s * wr[k]; az += s * wz[k]; an += s * wn[k];
        }
        float r = fsigmoid(gr + ar);
        float z = fsigmoid(gz + az);
        float nn2 = tanhf(gn + r * an);
        h = (1.f - z) * nn2 + z * h;
        if (yout) yout[((size_t)n * TT + (t0 + tc)) * HH + j] = h;
    }
    hstate[(size_t)n * HH + j] = h;
}

// ---------------- head: BN + relu + linear + log_softmax ----------------
__global__ __launch_bounds__(256) void k_head(const float* __restrict__ Hf,
                                              const float* __restrict__ g, const float* __restrict__ b,
                                              const float* __restrict__ m, const float* __restrict__ v,
                                              const float* __restrict__ W, const float* __restrict__ wb,
                                              float* __restrict__ out) {
    __shared__ float hb[4][HH];
    __shared__ float lg[4][CC];
    int tid = threadIdx.x;
    int n0 = blockIdx.x * 4;
    int wv = tid >> 6, lane = tid & 63;
    int n = n0 + wv;
    float x = Hf[(size_t)n * HH + lane];
    x = (x - m[lane]) * rsqrtf(v[lane] + EPSBN) * g[lane] + b[lane];
    hb[wv][lane] = fmaxf(x, 0.f);
    __syncthreads();
    if (tid < 4 * CC) {
        int nn = tid / CC, c = tid % CC;
        float acc = wb[c];
        for (int f = 0; f < HH; ++f) acc += hb[nn][f] * W[c * HH + f];
        lg[nn][c] = acc;
    }
    __syncthreads();
    if (tid < 4 * CC) {
        int nn = tid / CC, c = tid % CC;
        float mx = -1e30f;
#pragma unroll
        for (int i = 0; i < CC; ++i) mx = fmaxf(mx, lg[nn][i]);
        float s = 0.f;
#pragma unroll
        for (int i = 0; i < CC; ++i) s += __expf(lg[nn][i] - mx);
        out[(size_t)(n0 + nn) * CC + c] = lg[nn][c] - mx - __logf(s);
    }
}

// ---------------- launch ----------------
extern "C" void kernel_launch(void* const* d_in, const int* in_sizes, int n_in,
                              void* d_out, int out_size, void* d_ws, size_t ws_size,
                              hipStream_t stream) {
    const float* x_seq     = (const float*)d_in[0];
    const int*   edge_idx  = (const int*)d_in[1];
    const float* edge_w    = (const float*)d_in[2];
    const float* causal_w  = (const float*)d_in[3];
    const float* lin_in_w  = (const float*)d_in[4];
    const float* lin_in_b  = (const float*)d_in[5];
    const float* fusion_w  = (const float*)d_in[6];
    const float* fusion_b  = (const float*)d_in[7];
    const float* gcn_w0    = (const float*)d_in[8];
    const float* gcn_b0    = (const float*)d_in[9];
    const float* gcn_w1    = (const float*)d_in[10];
    const float* gcn_b1    = (const float*)d_in[11];
    const float* bn0_g = (const float*)d_in[12], *bn0_b = (const float*)d_in[13];
    const float* bn0_m = (const float*)d_in[14], *bn0_v = (const float*)d_in[15];
    const float* bn1_g = (const float*)d_in[16], *bn1_b = (const float*)d_in[17];
    const float* bn1_m = (const float*)d_in[18], *bn1_v = (const float*)d_in[19];
    const float* wih0 = (const float*)d_in[20], *whh0 = (const float*)d_in[21];
    const float* bih0 = (const float*)d_in[22], *bhh0 = (const float*)d_in[23];
    const float* wih1 = (const float*)d_in[24], *whh1 = (const float*)d_in[25];
    const float* bih1 = (const float*)d_in[26], *bhh1 = (const float*)d_in[27];
    const float* bno_g = (const float*)d_in[28], *bno_b = (const float*)d_in[29];
    const float* bno_m = (const float*)d_in[30], *bno_v = (const float*)d_in[31];
    const float* lout_w = (const float*)d_in[32], *lout_b = (const float*)d_in[33];
    float* out = (float*)d_out;

    float* wsf = (float*)d_ws;
    unsigned short* WCH = (unsigned short*)(wsf + OFF_WC);
    float* XA  = wsf + OFF_XA;
    float* XB  = wsf + OFF_XB;
    float* XC  = wsf + OFF_XC;
    unsigned short* XAT = (unsigned short*)(wsf + OFF_XC);
    float* DEG = wsf + OFF_DEG;
    int* CNT   = (int*)(wsf + OFF_CNT);
    int* CUR   = (int*)(wsf + OFF_CUR);
    int* OFFP  = (int*)(wsf + OFF_OFF);
    int* CSRS  = (int*)(wsf + OFF_CSRS);
    float* CSRN = wsf + OFF_CSRN;
    float* HST  = wsf + OFF_HST;
    float* GIb  = XB;

    // CSR + degree build
    k_zero<<<8, 256, 0, stream>>>(CNT, CUR, DEG);
    k_count<<<(ETOT + 255) / 256, 256, 0, stream>>>(edge_idx, edge_w, CNT, DEG);
    k_scan<<<1, 1024, 0, stream>>>(CNT, OFFP);
    k_fill<<<(ETOT + 255) / 256, 256, 0, stream>>>(edge_idx, edge_w, DEG, OFFP, CUR, CSRS, CSRN);

    hipMemsetAsync(WCH, 0, (size_t)2048 * 2048 * 2, stream);
    k_softmax<<<NN, 256, 0, stream>>>(causal_w, WCH);
    // lin_in -> XA [N,T,H] fp32
    k_lin2<<<NN, 256, 0, stream>>>(x_seq, lin_in_w, lin_in_b, XA);
    // transpose+cast: XA -> XAh_t bf16 [4096][2048]
    dim3 tg(THL / 64, 2048 / 64);
    k_tr<<<tg, 256, 0, stream>>>(XA, XAT);
    // x_agg = WCh @ X (MFMA bf16) -> XB fp32
    dim3 gg(THL / 128, 2048 / 128);
    k_gemm_bf<<<gg, 256, 0, stream>>>(WCH, XAT, XB);
    // fusion -> XC
    k_fus2<<<NN, 256, 0, stream>>>(XA, XB, fusion_w, fusion_b, XC);
    // GCN layer 0: XC -> XB (xw) -> XA (agg+bn+relu)
    k_xw2<<<NN, 256, 0, stream>>>(XC, gcn_w0, XB);
    dim3 ag(NN, 4);
    k_agg<<<ag, 256, 0, stream>>>(XB, OFFP, CSRS, CSRN, gcn_b0, bn0_g, bn0_b, bn0_m, bn0_v, XA);
    // GCN layer 1: XA -> XB -> XC
    k_xw2<<<NN, 256, 0, stream>>>(XA, gcn_w1, XB);
    k_agg<<<ag, 256, 0, stream>>>(XB, OFFP, CSRS, CSRN, gcn_b1, bn1_g, bn1_b, bn1_m, bn1_v, XC);

    // GRU layer 0: input XC -> all-t output H0 in XA (chunked over T)
    dim3 gig(NN * CHT / 64, 3);
    for (int c = 0; c < TT / CHT; ++c) {
        k_gi2<<<gig, 256, 0, stream>>>(XC, wih0, bih0, GIb, c * CHT);
        k_rec<<<NN / 4, 256, 0, stream>>>(GIb, whh0, bhh0, HST, XA, c * CHT, c == 0);
    }
    // GRU layer 1: input XA (H0) -> final h in HST
    for (int c = 0; c < TT / CHT; ++c) {
        k_gi2<<<gig, 256, 0, stream>>>(XA, wih1, bih1, GIb, c * CHT);
        k_rec<<<NN / 4, 256, 0, stream>>>(GIb, whh1, bhh1, HST, (float*)nullptr, c * CHT, c == 0);
    }
    // head
    k_head<<<NN / 4, 256, 0, stream>>>(HST, bno_g, bno_b, bno_m, bno_v, lout_w, lout_b, out);
}